// Round 7
// baseline (6757.338 us; speedup 1.0000x reference)
//
#include <hip/hip_runtime.h>
#include <cstdint>
#include <cstddef>

// =====================================================================
// PyrDCNAlign — direct fp32 implementation
// B=8, C=64, L1=128x128, L2=64x64, L3=32x32
// r6: identical to r3/r4/r5 (rounds 1-6 all infra acquisition timeouts;
//     awaiting first real bench of this source).
// =====================================================================

#define BB 8
#define CC 64

// ---------------- bicubic resize, scale 0.5 (fixed weights) ----------------
__global__ __launch_bounds__(256) void k_down(const float* __restrict__ in,
                                              float* __restrict__ out,
                                              int BC, int Hin, int Win) {
  const int Ho = Hin >> 1, Wo = Win >> 1;
  const float W4[4] = {-0.09375f, 0.59375f, 0.59375f, -0.09375f};
  int total = BC * Ho * Wo;
  for (int idx = blockIdx.x * 256 + threadIdx.x; idx < total; idx += gridDim.x * 256) {
    int x = idx % Wo;
    int y = (idx / Wo) % Ho;
    int bc = idx / (Wo * Ho);
    const float* src = in + (size_t)bc * Hin * Win;
    float s = 0.f;
#pragma unroll
    for (int i = 0; i < 4; ++i) {
      int yy = 2 * y - 1 + i;
      yy = min(max(yy, 0), Hin - 1);
      const float* row = src + (size_t)yy * Win;
      float rs = 0.f;
#pragma unroll
      for (int j = 0; j < 4; ++j) {
        int xx = 2 * x - 1 + j;
        xx = min(max(xx, 0), Win - 1);
        rs = fmaf(W4[j], row[xx], rs);
      }
      s = fmaf(W4[i], rs, s);
    }
    out[idx] = s;
  }
}

// ---------------- bicubic resize, scale 2.0 (fixed weights by parity) -------
__global__ __launch_bounds__(256) void k_up(const float* __restrict__ in,
                                            float* __restrict__ out,
                                            int BC, int Hin, int Win) {
  const int Ho = Hin << 1, Wo = Win << 1;
  const float WE[4] = {-0.03515625f, 0.26171875f, 0.87890625f, -0.10546875f};
  int total = BC * Ho * Wo;
  for (int idx = blockIdx.x * 256 + threadIdx.x; idx < total; idx += gridDim.x * 256) {
    int x = idx % Wo;
    int y = (idx / Wo) % Ho;
    int bc = idx / (Wo * Ho);
    const float* src = in + (size_t)bc * Hin * Win;
    int fy = (y & 1) ? (y >> 1) : (y >> 1) - 1;
    int fx = (x & 1) ? (x >> 1) : (x >> 1) - 1;
    float s = 0.f;
#pragma unroll
    for (int i = 0; i < 4; ++i) {
      float wy = (y & 1) ? WE[3 - i] : WE[i];
      int yy = min(max(fy - 1 + i, 0), Hin - 1);
      const float* row = src + (size_t)yy * Win;
      float rs = 0.f;
#pragma unroll
      for (int j = 0; j < 4; ++j) {
        float wx = (x & 1) ? WE[3 - j] : WE[j];
        int xx = min(max(fx - 1 + j, 0), Win - 1);
        rs = fmaf(wx, row[xx], rs);
      }
      s = fmaf(wy, rs, s);
    }
    out[idx] = s;
  }
}

// ---------------- weight transpose: [O][Ci][K] -> [K][Ci][O] ----------------
__global__ __launch_bounds__(256) void k_wtrans(const float* __restrict__ in,
                                                float* __restrict__ out,
                                                int COUT, int CIN, int K) {
  int total = COUT * CIN * K;
  int i = blockIdx.x * 256 + threadIdx.x;
  if (i >= total) return;
  int k = i % K;
  int c = (i / K) % CIN;
  int oc = i / (K * CIN);
  out[((size_t)k * CIN + c) * COUT + oc] = in[i];
}

// ---------------- 5x5 conv, Cin = 64+64 (concat of two ptrs), pad=2 ---------
// block = 256 threads = 16x16 output tile; 4 channels staged per barrier.
template <int COUT>
__global__ __launch_bounds__(256) void k_conv5(
    const float* __restrict__ inA, const float* __restrict__ inB,
    const float* __restrict__ wgt, const float* __restrict__ bias,
    float* __restrict__ out, int H, int W,
    long long obatch, long long ochoff) {
  __shared__ float tile[4][400];
  const int tilesX = W >> 4;
  const int tpb = tilesX * (H >> 4);
  const int b = blockIdx.x / tpb;
  const int t = blockIdx.x - b * tpb;
  const int ty0 = (t / tilesX) << 4;
  const int tx0 = (t % tilesX) << 4;
  const int tx = threadIdx.x & 15;
  const int ty = threadIdx.x >> 4;
  const int HW = H * W;

  float acc[COUT];
#pragma unroll
  for (int i = 0; i < COUT; ++i) acc[i] = bias[i];

  for (int cc0 = 0; cc0 < 128; cc0 += 4) {
    // stage channels cc0..cc0+3: 1600 floats by 256 threads
    for (int i = threadIdx.x; i < 1600; i += 256) {
      int ch = i / 400;
      int r = i - ch * 400;
      int ly = r / 20, lx = r - ly * 20;
      int cc = cc0 + ch;
      const float* src = (cc < 64) ? (inA + ((size_t)b * 64 + cc) * HW)
                                   : (inB + ((size_t)b * 64 + (cc - 64)) * HW);
      int gy = ty0 + ly - 2, gx = tx0 + lx - 2;
      float v = 0.f;
      if (gy >= 0 && gy < H && gx >= 0 && gx < W) v = src[(size_t)gy * W + gx];
      tile[ch][r] = v;
    }
    __syncthreads();
#pragma unroll
    for (int q = 0; q < 4; ++q) {
      const int cc = cc0 + q;
      float r[25];
#pragma unroll
      for (int i = 0; i < 5; ++i)
#pragma unroll
        for (int j = 0; j < 5; ++j)
          r[i * 5 + j] = tile[q][(ty + i) * 20 + tx + j];
#pragma unroll
      for (int oc = 0; oc < COUT; ++oc) {
        const float* wo = wgt + ((size_t)oc * 128 + cc) * 25;
        float a = acc[oc];
#pragma unroll
        for (int p = 0; p < 25; ++p) a = fmaf(wo[p], r[p], a);
        acc[oc] = a;
      }
    }
    __syncthreads();
  }
  float* op = out + (size_t)b * obatch + ochoff + (size_t)(ty0 + ty) * W + tx0 + tx;
#pragma unroll
  for (int oc = 0; oc < COUT; ++oc) op[(size_t)oc * HW] = acc[oc];
}

// ---------------- 1x1 conv over concat(inA[CINA], inB[CINB]) ----------------
// wT layout: [c][COUT] (transposed) so weight scalar-loads are contiguous.
template <int CINA, int CINB, int COUT>
__global__ __launch_bounds__(256) void k_conv1x1(
    const float* __restrict__ inA, const float* __restrict__ inB,
    const float* __restrict__ wT, const float* __restrict__ bias,
    float* __restrict__ out, int HW, long long obatch, long long ochoff) {
  const int b = blockIdx.y;
  const int p = blockIdx.x * 256 + threadIdx.x;
  if (p >= HW) return;
  float acc[COUT];
#pragma unroll
  for (int i = 0; i < COUT; ++i) acc[i] = bias[i];
  const float* pa = inA + (size_t)b * CINA * HW + p;
  for (int c = 0; c < CINA; ++c) {
    float v = pa[(size_t)c * HW];
    const float* w = wT + (size_t)c * COUT;
#pragma unroll
    for (int oc = 0; oc < COUT; ++oc) acc[oc] = fmaf(w[oc], v, acc[oc]);
  }
  const float* pb = inB + (size_t)b * CINB * HW + p;
  for (int c = 0; c < CINB; ++c) {
    float v = pb[(size_t)c * HW];
    const float* w = wT + (size_t)(CINA + c) * COUT;
#pragma unroll
    for (int oc = 0; oc < COUT; ++oc) acc[oc] = fmaf(w[oc], v, acc[oc]);
  }
  float* op = out + (size_t)b * obatch + ochoff + p;
#pragma unroll
  for (int oc = 0; oc < COUT; ++oc) op[(size_t)oc * HW] = acc[oc];
}

// ---------------- modulated deformable conv 3x3, dg=1 ----------------------
// om channels: 2k=dy_k, 2k+1=dx_k (k=0..8 row-major), 18+k=mask logit.
// wT layout: [k][c][COUT] (transposed).
template <int CIN, int COUT>
__global__ __launch_bounds__(256) void k_dcn(
    const float* __restrict__ fn, const float* __restrict__ om,
    const float* __restrict__ wT, const float* __restrict__ bias,
    float* __restrict__ out, int H, int W,
    long long omBatch, long long outBatch, long long outChOff) {
  const int b = blockIdx.y;
  const int p = blockIdx.x * 256 + threadIdx.x;
  const int HW = H * W;
  if (p >= HW) return;
  const int y = p / W;
  const int x = p - y * W;
  const float* omb = om + (size_t)b * omBatch;
  const float* fnb = fn + (size_t)b * CIN * HW;

  float acc[COUT];
#pragma unroll
  for (int i = 0; i < COUT; ++i) acc[i] = bias[i];

  for (int k = 0; k < 9; ++k) {
    float dy = omb[(size_t)(2 * k) * HW + p];
    float dx = omb[(size_t)(2 * k + 1) * HW + p];
    float ml = omb[(size_t)(18 + k) * HW + p];
    float m = 1.f / (1.f + __expf(-ml));
    float py = (float)(y + (k / 3) - 1) + dy;
    float px = (float)(x + (k % 3) - 1) + dx;
    float y0f = floorf(py), x0f = floorf(px);
    float ly = py - y0f, lx = px - x0f;
    int y0 = (int)y0f, x0 = (int)x0f;
    int y1 = y0 + 1, x1 = x0 + 1;
    float w00 = (1.f - ly) * (1.f - lx) * m;
    float w01 = (1.f - ly) * lx * m;
    float w10 = ly * (1.f - lx) * m;
    float w11 = ly * lx * m;
    bool vy0 = ((unsigned)y0 < (unsigned)H);
    bool vy1 = ((unsigned)y1 < (unsigned)H);
    bool vx0 = ((unsigned)x0 < (unsigned)W);
    bool vx1 = ((unsigned)x1 < (unsigned)W);
    if (!(vy0 && vx0)) w00 = 0.f;
    if (!(vy0 && vx1)) w01 = 0.f;
    if (!(vy1 && vx0)) w10 = 0.f;
    if (!(vy1 && vx1)) w11 = 0.f;
    int cy0 = min(max(y0, 0), H - 1), cy1 = min(max(y1, 0), H - 1);
    int cx0 = min(max(x0, 0), W - 1), cx1 = min(max(x1, 0), W - 1);
    int o00 = cy0 * W + cx0, o01 = cy0 * W + cx1;
    int o10 = cy1 * W + cx0, o11 = cy1 * W + cx1;
    for (int c = 0; c < CIN; ++c) {
      const float* f = fnb + (size_t)c * HW;
      float val = w00 * f[o00] + w01 * f[o01] + w10 * f[o10] + w11 * f[o11];
      const float* w = wT + ((size_t)k * CIN + c) * COUT;
#pragma unroll
      for (int oc = 0; oc < COUT; ++oc) acc[oc] = fmaf(w[oc], val, acc[oc]);
    }
  }
  float* op = out + (size_t)b * outBatch + outChOff + p;
#pragma unroll
  for (int oc = 0; oc < COUT; ++oc) op[(size_t)oc * HW] = acc[oc];
}

// =====================================================================
extern "C" void kernel_launch(void* const* d_in, const int* in_sizes, int n_in,
                              void* d_out, int out_size, void* d_ws, size_t ws_size,
                              hipStream_t stream) {
  const float* feat_c = (const float*)d_in[0];
  const float* feat_n = (const float*)d_in[1];
  const float* w_om1 = (const float*)d_in[2];  const float* b_om1 = (const float*)d_in[3];
  const float* w_om2 = (const float*)d_in[4];  const float* b_om2 = (const float*)d_in[5];
  const float* w_om3 = (const float*)d_in[6];  const float* b_om3 = (const float*)d_in[7];
  const float* w_omc = (const float*)d_in[8];  const float* b_omc = (const float*)d_in[9];
  const float* w_f23 = (const float*)d_in[10]; const float* b_f23 = (const float*)d_in[11];
  const float* w_f12 = (const float*)d_in[12]; const float* b_f12 = (const float*)d_in[13];
  const float* w_a23 = (const float*)d_in[14]; const float* b_a23 = (const float*)d_in[15];
  const float* w_a12 = (const float*)d_in[16]; const float* b_a12 = (const float*)d_in[17];
  const float* w_d1 = (const float*)d_in[18];  const float* b_d1 = (const float*)d_in[19];
  const float* w_d2 = (const float*)d_in[20];  const float* b_d2 = (const float*)d_in[21];
  const float* w_d3 = (const float*)d_in[22];  const float* b_d3 = (const float*)d_in[23];
  const float* w_dc = (const float*)d_in[24];  const float* b_dc = (const float*)d_in[25];

  float* out = (float*)d_out;
  float* ws = (float*)d_ws;

  const int H1 = 128, W1 = 128, HW1s = 16384;
  const int H2 = 64,  W2 = 64,  HW2s = 4096;
  const int H3 = 32,  W3 = 32,  HW3s = 1024;
  const int B = BB;

  // ---- workspace arena (fp32 elements), lifetime-checked aliases ----
  size_t off = 0;
  auto alloc = [&](size_t n) { float* p = ws + off; off += n; return p; };
  float* fc2     = alloc((size_t)B * CC * HW2s);   // aliased later: a2_raw
  float* fn2     = alloc((size_t)B * CC * HW2s);
  float* fc3     = alloc((size_t)B * CC * HW3s);   // aliased later: a3
  float* fn3     = alloc((size_t)B * CC * HW3s);
  float* om3     = alloc((size_t)B * 27 * HW3s);
  float* om2_raw = alloc((size_t)B * 27 * HW2s);
  float* om3_up  = alloc((size_t)B * 27 * HW2s);
  float* om2     = alloc((size_t)B * 27 * HW2s);
  float* om1_raw = alloc((size_t)B * 27 * HW1s);
  float* om2_up  = alloc((size_t)B * 27 * HW1s);   // aliased later: a3_up
  float* a2      = alloc((size_t)B * CC * HW2s);
  float* a1_raw  = alloc((size_t)B * CC * HW1s);
  float* a2_up   = alloc((size_t)B * CC * HW1s);
  float* a1      = alloc((size_t)B * CC * HW1s);
  float* wt_d1   = alloc(64 * 64 * 9);
  float* wt_d2   = alloc(64 * 64 * 9);
  float* wt_d3   = alloc(64 * 64 * 9);
  float* wt_dc   = alloc(64 * 64 * 9);
  float* wt_f23  = alloc(27 * 54);
  float* wt_f12  = alloc(27 * 54);
  float* wt_a23  = alloc(64 * 128);
  float* wt_a12  = alloc(64 * 128);
  if (ws_size < off * sizeof(float)) return;  // workspace too small: bail out

  float* a2_raw = fc2;     // fc2 dead after om2_raw conv
  float* a3     = fc3;     // fc3 dead after om3 conv
  float* a3_up  = om2_up;  // om2_up dead after om1

  float* out1 = out + (size_t)B * CC * HW1s;  // second output: [B][54][128][128]

  dim3 blk(256);
  int g;

  // ---- weight transposes (read-only inputs; run first) ----
  k_wtrans<<<(64 * 64 * 9 + 255) / 256, blk, 0, stream>>>(w_d1, wt_d1, 64, 64, 9);
  k_wtrans<<<(64 * 64 * 9 + 255) / 256, blk, 0, stream>>>(w_d2, wt_d2, 64, 64, 9);
  k_wtrans<<<(64 * 64 * 9 + 255) / 256, blk, 0, stream>>>(w_d3, wt_d3, 64, 64, 9);
  k_wtrans<<<(64 * 64 * 9 + 255) / 256, blk, 0, stream>>>(w_dc, wt_dc, 64, 64, 9);
  k_wtrans<<<(27 * 54 + 255) / 256, blk, 0, stream>>>(w_f23, wt_f23, 27, 54, 1);
  k_wtrans<<<(27 * 54 + 255) / 256, blk, 0, stream>>>(w_f12, wt_f12, 27, 54, 1);
  k_wtrans<<<(64 * 128 + 255) / 256, blk, 0, stream>>>(w_a23, wt_a23, 64, 128, 1);
  k_wtrans<<<(64 * 128 + 255) / 256, blk, 0, stream>>>(w_a12, wt_a12, 64, 128, 1);

  // ---- pyramid downsample ----
  g = ((int)((size_t)B * CC * HW2s) + 255) / 256;
  k_down<<<g, blk, 0, stream>>>(feat_c, fc2, B * CC, H1, W1);
  k_down<<<g, blk, 0, stream>>>(feat_n, fn2, B * CC, H1, W1);
  g = ((int)((size_t)B * CC * HW3s) + 255) / 256;
  k_down<<<g, blk, 0, stream>>>(fc2, fc3, B * CC, H2, W2);
  k_down<<<g, blk, 0, stream>>>(fn2, fn3, B * CC, H2, W2);

  // ---- offset/mask branch ----
  k_conv5<27><<<B * (H3 / 16) * (W3 / 16), blk, 0, stream>>>(
      fc3, fn3, w_om3, b_om3, om3, H3, W3, 27LL * HW3s, 0LL);
  k_conv5<27><<<B * (H2 / 16) * (W2 / 16), blk, 0, stream>>>(
      fc2, fn2, w_om2, b_om2, om2_raw, H2, W2, 27LL * HW2s, 0LL);
  g = ((int)((size_t)B * 27 * HW2s) + 255) / 256;
  k_up<<<g, blk, 0, stream>>>(om3, om3_up, B * 27, H3, W3);
  {
    dim3 gg(HW2s / 256, B);
    k_conv1x1<27, 27, 27><<<gg, blk, 0, stream>>>(
        om2_raw, om3_up, wt_f23, b_f23, om2, HW2s, 27LL * HW2s, 0LL);
  }
  k_conv5<27><<<B * (H1 / 16) * (W1 / 16), blk, 0, stream>>>(
      feat_c, feat_n, w_om1, b_om1, om1_raw, H1, W1, 27LL * HW1s, 0LL);
  g = ((int)((size_t)B * 27 * HW1s) + 255) / 256;
  k_up<<<g, blk, 0, stream>>>(om2, om2_up, B * 27, H2, W2);
  {
    dim3 gg(HW1s / 256, B);  // om1 -> d_out second output, channels 0..26
    k_conv1x1<27, 27, 27><<<gg, blk, 0, stream>>>(
        om1_raw, om2_up, wt_f12, b_f12, out1, HW1s, 54LL * HW1s, 0LL);
  }

  // ---- aligned-feature branch ----
  {
    dim3 gg(HW3s / 256, B);
    k_dcn<64, 64><<<gg, blk, 0, stream>>>(
        fn3, om3, wt_d3, b_d3, a3, H3, W3, 27LL * HW3s, 64LL * HW3s, 0LL);
  }
  {
    dim3 gg(HW2s / 256, B);
    k_dcn<64, 64><<<gg, blk, 0, stream>>>(
        fn2, om2, wt_d2, b_d2, a2_raw, H2, W2, 27LL * HW2s, 64LL * HW2s, 0LL);
  }
  g = ((int)((size_t)B * CC * HW2s) + 255) / 256;
  k_up<<<g, blk, 0, stream>>>(a3, a3_up, B * CC, H3, W3);
  {
    dim3 gg(HW2s / 256, B);
    k_conv1x1<64, 64, 64><<<gg, blk, 0, stream>>>(
        a2_raw, a3_up, wt_a23, b_a23, a2, HW2s, 64LL * HW2s, 0LL);
  }
  {
    dim3 gg(HW1s / 256, B);  // om1 read back from d_out (channels 0..26 of [54])
    k_dcn<64, 64><<<gg, blk, 0, stream>>>(
        feat_n, out1, wt_d1, b_d1, a1_raw, H1, W1, 54LL * HW1s, 64LL * HW1s, 0LL);
  }
  g = ((int)((size_t)B * CC * HW1s) + 255) / 256;
  k_up<<<g, blk, 0, stream>>>(a2, a2_up, B * CC, H2, W2);
  {
    dim3 gg(HW1s / 256, B);
    k_conv1x1<64, 64, 64><<<gg, blk, 0, stream>>>(
        a1_raw, a2_up, wt_a12, b_a12, a1, HW1s, 64LL * HW1s, 0LL);
  }

  // ---- final: omc (-> d_out channels 27..53 of output 1), then ac ----
  k_conv5<27><<<B * (H1 / 16) * (W1 / 16), blk, 0, stream>>>(
      feat_c, a1, w_omc, b_omc, out1, H1, W1, 54LL * HW1s, 27LL * HW1s);
  {
    dim3 gg(HW1s / 256, B);
    k_dcn<64, 64><<<gg, blk, 0, stream>>>(
        a1, out1 + 27LL * HW1s, wt_dc, b_dc, out, H1, W1,
        54LL * HW1s, 64LL * HW1s, 0LL);
  }
}

// Round 8
// 4048.981 us; speedup vs baseline: 1.6689x; 1.6689x over previous
//
#include <hip/hip_runtime.h>
#include <cstdint>
#include <cstddef>

// =====================================================================
// PyrDCNAlign — fp32, r7: conv5 weight path fixed.
//   Diagnosis (r7 counters): k_conv5 1380us/dispatch, VALUBusy 1%,
//   occupancy 1.5% -> latency-bound on per-thread uniform global weight
//   loads with no TLP. Fix: pre-transposed weights + LDS broadcast +
//   tap-major FMA order (chain-free). Per-acc summation order unchanged.
// =====================================================================

#define BB 8
#define CC 64

// ---------------- bicubic resize, scale 0.5 (fixed weights) ----------------
__global__ __launch_bounds__(256) void k_down(const float* __restrict__ in,
                                              float* __restrict__ out,
                                              int BC, int Hin, int Win) {
  const int Ho = Hin >> 1, Wo = Win >> 1;
  const float W4[4] = {-0.09375f, 0.59375f, 0.59375f, -0.09375f};
  int total = BC * Ho * Wo;
  for (int idx = blockIdx.x * 256 + threadIdx.x; idx < total; idx += gridDim.x * 256) {
    int x = idx % Wo;
    int y = (idx / Wo) % Ho;
    int bc = idx / (Wo * Ho);
    const float* src = in + (size_t)bc * Hin * Win;
    float s = 0.f;
#pragma unroll
    for (int i = 0; i < 4; ++i) {
      int yy = 2 * y - 1 + i;
      yy = min(max(yy, 0), Hin - 1);
      const float* row = src + (size_t)yy * Win;
      float rs = 0.f;
#pragma unroll
      for (int j = 0; j < 4; ++j) {
        int xx = 2 * x - 1 + j;
        xx = min(max(xx, 0), Win - 1);
        rs = fmaf(W4[j], row[xx], rs);
      }
      s = fmaf(W4[i], rs, s);
    }
    out[idx] = s;
  }
}

// ---------------- bicubic resize, scale 2.0 (fixed weights by parity) -------
__global__ __launch_bounds__(256) void k_up(const float* __restrict__ in,
                                            float* __restrict__ out,
                                            int BC, int Hin, int Win) {
  const int Ho = Hin << 1, Wo = Win << 1;
  const float WE[4] = {-0.03515625f, 0.26171875f, 0.87890625f, -0.10546875f};
  int total = BC * Ho * Wo;
  for (int idx = blockIdx.x * 256 + threadIdx.x; idx < total; idx += gridDim.x * 256) {
    int x = idx % Wo;
    int y = (idx / Wo) % Ho;
    int bc = idx / (Wo * Ho);
    const float* src = in + (size_t)bc * Hin * Win;
    int fy = (y & 1) ? (y >> 1) : (y >> 1) - 1;
    int fx = (x & 1) ? (x >> 1) : (x >> 1) - 1;
    float s = 0.f;
#pragma unroll
    for (int i = 0; i < 4; ++i) {
      float wy = (y & 1) ? WE[3 - i] : WE[i];
      int yy = min(max(fy - 1 + i, 0), Hin - 1);
      const float* row = src + (size_t)yy * Win;
      float rs = 0.f;
#pragma unroll
      for (int j = 0; j < 4; ++j) {
        float wx = (x & 1) ? WE[3 - j] : WE[j];
        int xx = min(max(fx - 1 + j, 0), Win - 1);
        rs = fmaf(wx, row[xx], rs);
      }
      s = fmaf(wy, rs, s);
    }
    out[idx] = s;
  }
}

// ---------------- weight transpose: [O][Ci][K] -> [K][Ci][O] ----------------
__global__ __launch_bounds__(256) void k_wtrans(const float* __restrict__ in,
                                                float* __restrict__ out,
                                                int COUT, int CIN, int K) {
  int total = COUT * CIN * K;
  int i = blockIdx.x * 256 + threadIdx.x;
  if (i >= total) return;
  int k = i % K;
  int c = (i / K) % CIN;
  int oc = i / (K * CIN);
  out[((size_t)k * CIN + c) * COUT + oc] = in[i];
}

// ---------------- conv5 weight transpose: [27][128][25] -> [128][25][27] ----
__global__ __launch_bounds__(256) void k_wt5(const float* __restrict__ in,
                                             float* __restrict__ out) {
  int i = blockIdx.x * 256 + threadIdx.x;
  if (i >= 27 * 128 * 25) return;
  int oc = i / (128 * 25);
  int rem = i - oc * (128 * 25);
  int c = rem / 25, t = rem - c * 25;
  out[((size_t)c * 25 + t) * 27 + oc] = in[i];
}

// ---------------- 5x5 conv, Cin = 64+64 (concat of two ptrs), pad=2 ---------
// block = 256 threads = 16x16 output tile; 4 channels staged per barrier.
// wt5: transposed weights [128][25][27]; staged into LDS, broadcast reads.
// FMA order tap-major (chain-free ILP across 27 accumulators).
__global__ __launch_bounds__(256) void k_conv5(
    const float* __restrict__ inA, const float* __restrict__ inB,
    const float* __restrict__ wt5, const float* __restrict__ bias,
    float* __restrict__ out, int H, int W,
    long long obatch, long long ochoff) {
  __shared__ float tile[4][400];
  __shared__ float wlds[4 * 700];  // [q][t][28] (27 used, pad to 28 for f4 align)
  const int tilesX = W >> 4;
  const int tpb = tilesX * (H >> 4);
  const int b = blockIdx.x / tpb;
  const int t = blockIdx.x - b * tpb;
  const int ty0 = (t / tilesX) << 4;
  const int tx0 = (t % tilesX) << 4;
  const int tx = threadIdx.x & 15;
  const int ty = threadIdx.x >> 4;
  const int HW = H * W;

  float acc[27];
#pragma unroll
  for (int i = 0; i < 27; ++i) acc[i] = bias[i];

  for (int cc0 = 0; cc0 < 128; cc0 += 4) {
    // stage activations: channels cc0..cc0+3 (1600 floats)
    for (int i = threadIdx.x; i < 1600; i += 256) {
      int ch = i / 400;
      int r = i - ch * 400;
      int ly = r / 20, lx = r - ly * 20;
      int cc = cc0 + ch;
      const float* src = (cc < 64) ? (inA + ((size_t)b * 64 + cc) * HW)
                                   : (inB + ((size_t)b * 64 + (cc - 64)) * HW);
      int gy = ty0 + ly - 2, gx = tx0 + lx - 2;
      float v = 0.f;
      if (gy >= 0 && gy < H && gx >= 0 && gx < W) v = src[(size_t)gy * W + gx];
      tile[ch][r] = v;
    }
    // stage weights: 4 ch x 25 taps x 27 oc (coalesced from wt5)
    for (int i = threadIdx.x; i < 2700; i += 256) {
      int q = i / 675, r5 = i - q * 675;       // r5 = t*27 + oc
      int tt = r5 / 27, oc = r5 - tt * 27;
      wlds[q * 700 + tt * 28 + oc] = wt5[(size_t)(cc0 + q) * 675 + r5];
    }
    __syncthreads();
#pragma unroll
    for (int q = 0; q < 4; ++q) {
      float r[25];
#pragma unroll
      for (int i = 0; i < 5; ++i)
#pragma unroll
        for (int j = 0; j < 5; ++j)
          r[i * 5 + j] = tile[q][(ty + i) * 20 + tx + j];
#pragma unroll
      for (int tt = 0; tt < 25; ++tt) {
        float rt = r[tt];
        const float4* wp = (const float4*)&wlds[q * 700 + tt * 28];
        float wv[28];
#pragma unroll
        for (int u = 0; u < 7; ++u) *(float4*)&wv[4 * u] = wp[u];
#pragma unroll
        for (int oc = 0; oc < 27; ++oc) acc[oc] = fmaf(wv[oc], rt, acc[oc]);
      }
    }
    __syncthreads();
  }
  float* op = out + (size_t)b * obatch + ochoff + (size_t)(ty0 + ty) * W + tx0 + tx;
#pragma unroll
  for (int oc = 0; oc < 27; ++oc) op[(size_t)oc * HW] = acc[oc];
}

// ---------------- 1x1 conv over concat(inA[CINA], inB[CINB]) ----------------
// wT layout: [c][COUT] (transposed) so weight scalar-loads are contiguous.
template <int CINA, int CINB, int COUT>
__global__ __launch_bounds__(256) void k_conv1x1(
    const float* __restrict__ inA, const float* __restrict__ inB,
    const float* __restrict__ wT, const float* __restrict__ bias,
    float* __restrict__ out, int HW, long long obatch, long long ochoff) {
  const int b = blockIdx.y;
  const int p = blockIdx.x * 256 + threadIdx.x;
  if (p >= HW) return;
  float acc[COUT];
#pragma unroll
  for (int i = 0; i < COUT; ++i) acc[i] = bias[i];
  const float* pa = inA + (size_t)b * CINA * HW + p;
  for (int c = 0; c < CINA; ++c) {
    float v = pa[(size_t)c * HW];
    const float* w = wT + (size_t)c * COUT;
#pragma unroll
    for (int oc = 0; oc < COUT; ++oc) acc[oc] = fmaf(w[oc], v, acc[oc]);
  }
  const float* pb = inB + (size_t)b * CINB * HW + p;
  for (int c = 0; c < CINB; ++c) {
    float v = pb[(size_t)c * HW];
    const float* w = wT + (size_t)(CINA + c) * COUT;
#pragma unroll
    for (int oc = 0; oc < COUT; ++oc) acc[oc] = fmaf(w[oc], v, acc[oc]);
  }
  float* op = out + (size_t)b * obatch + ochoff + p;
#pragma unroll
  for (int oc = 0; oc < COUT; ++oc) op[(size_t)oc * HW] = acc[oc];
}

// ---------------- modulated deformable conv 3x3, dg=1 ----------------------
// om channels: 2k=dy_k, 2k+1=dx_k (k=0..8 row-major), 18+k=mask logit.
// wT layout: [k][c][COUT] (transposed).
template <int CIN, int COUT>
__global__ __launch_bounds__(256) void k_dcn(
    const float* __restrict__ fn, const float* __restrict__ om,
    const float* __restrict__ wT, const float* __restrict__ bias,
    float* __restrict__ out, int H, int W,
    long long omBatch, long long outBatch, long long outChOff) {
  const int b = blockIdx.y;
  const int p = blockIdx.x * 256 + threadIdx.x;
  const int HW = H * W;
  if (p >= HW) return;
  const int y = p / W;
  const int x = p - y * W;
  const float* omb = om + (size_t)b * omBatch;
  const float* fnb = fn + (size_t)b * CIN * HW;

  float acc[COUT];
#pragma unroll
  for (int i = 0; i < COUT; ++i) acc[i] = bias[i];

  for (int k = 0; k < 9; ++k) {
    float dy = omb[(size_t)(2 * k) * HW + p];
    float dx = omb[(size_t)(2 * k + 1) * HW + p];
    float ml = omb[(size_t)(18 + k) * HW + p];
    float m = 1.f / (1.f + __expf(-ml));
    float py = (float)(y + (k / 3) - 1) + dy;
    float px = (float)(x + (k % 3) - 1) + dx;
    float y0f = floorf(py), x0f = floorf(px);
    float ly = py - y0f, lx = px - x0f;
    int y0 = (int)y0f, x0 = (int)x0f;
    int y1 = y0 + 1, x1 = x0 + 1;
    float w00 = (1.f - ly) * (1.f - lx) * m;
    float w01 = (1.f - ly) * lx * m;
    float w10 = ly * (1.f - lx) * m;
    float w11 = ly * lx * m;
    bool vy0 = ((unsigned)y0 < (unsigned)H);
    bool vy1 = ((unsigned)y1 < (unsigned)H);
    bool vx0 = ((unsigned)x0 < (unsigned)W);
    bool vx1 = ((unsigned)x1 < (unsigned)W);
    if (!(vy0 && vx0)) w00 = 0.f;
    if (!(vy0 && vx1)) w01 = 0.f;
    if (!(vy1 && vx0)) w10 = 0.f;
    if (!(vy1 && vx1)) w11 = 0.f;
    int cy0 = min(max(y0, 0), H - 1), cy1 = min(max(y1, 0), H - 1);
    int cx0 = min(max(x0, 0), W - 1), cx1 = min(max(x1, 0), W - 1);
    int o00 = cy0 * W + cx0, o01 = cy0 * W + cx1;
    int o10 = cy1 * W + cx0, o11 = cy1 * W + cx1;
    for (int c = 0; c < CIN; ++c) {
      const float* f = fnb + (size_t)c * HW;
      float val = w00 * f[o00] + w01 * f[o01] + w10 * f[o10] + w11 * f[o11];
      const float* w = wT + ((size_t)k * CIN + c) * COUT;
#pragma unroll
      for (int oc = 0; oc < COUT; ++oc) acc[oc] = fmaf(w[oc], val, acc[oc]);
    }
  }
  float* op = out + (size_t)b * outBatch + outChOff + p;
#pragma unroll
  for (int oc = 0; oc < COUT; ++oc) op[(size_t)oc * HW] = acc[oc];
}

// =====================================================================
extern "C" void kernel_launch(void* const* d_in, const int* in_sizes, int n_in,
                              void* d_out, int out_size, void* d_ws, size_t ws_size,
                              hipStream_t stream) {
  const float* feat_c = (const float*)d_in[0];
  const float* feat_n = (const float*)d_in[1];
  const float* w_om1 = (const float*)d_in[2];  const float* b_om1 = (const float*)d_in[3];
  const float* w_om2 = (const float*)d_in[4];  const float* b_om2 = (const float*)d_in[5];
  const float* w_om3 = (const float*)d_in[6];  const float* b_om3 = (const float*)d_in[7];
  const float* w_omc = (const float*)d_in[8];  const float* b_omc = (const float*)d_in[9];
  const float* w_f23 = (const float*)d_in[10]; const float* b_f23 = (const float*)d_in[11];
  const float* w_f12 = (const float*)d_in[12]; const float* b_f12 = (const float*)d_in[13];
  const float* w_a23 = (const float*)d_in[14]; const float* b_a23 = (const float*)d_in[15];
  const float* w_a12 = (const float*)d_in[16]; const float* b_a12 = (const float*)d_in[17];
  const float* w_d1 = (const float*)d_in[18];  const float* b_d1 = (const float*)d_in[19];
  const float* w_d2 = (const float*)d_in[20];  const float* b_d2 = (const float*)d_in[21];
  const float* w_d3 = (const float*)d_in[22];  const float* b_d3 = (const float*)d_in[23];
  const float* w_dc = (const float*)d_in[24];  const float* b_dc = (const float*)d_in[25];

  float* out = (float*)d_out;
  float* ws = (float*)d_ws;

  const int H1 = 128, W1 = 128, HW1s = 16384;
  const int H2 = 64,  W2 = 64,  HW2s = 4096;
  const int H3 = 32,  W3 = 32,  HW3s = 1024;
  const int B = BB;

  // ---- workspace arena (fp32 elements), lifetime-checked aliases ----
  size_t off = 0;
  auto alloc = [&](size_t n) { float* p = ws + off; off += n; return p; };
  float* fc2     = alloc((size_t)B * CC * HW2s);   // aliased later: a2_raw
  float* fn2     = alloc((size_t)B * CC * HW2s);
  float* fc3     = alloc((size_t)B * CC * HW3s);   // aliased later: a3
  float* fn3     = alloc((size_t)B * CC * HW3s);
  float* om3     = alloc((size_t)B * 27 * HW3s);
  float* om2_raw = alloc((size_t)B * 27 * HW2s);
  float* om3_up  = alloc((size_t)B * 27 * HW2s);
  float* om2     = alloc((size_t)B * 27 * HW2s);
  float* om1_raw = alloc((size_t)B * 27 * HW1s);
  float* om2_up  = alloc((size_t)B * 27 * HW1s);   // aliased later: a3_up
  float* a2      = alloc((size_t)B * CC * HW2s);
  float* a1_raw  = alloc((size_t)B * CC * HW1s);
  float* a2_up   = alloc((size_t)B * CC * HW1s);
  float* a1      = alloc((size_t)B * CC * HW1s);
  float* wt_d1   = alloc(64 * 64 * 9);
  float* wt_d2   = alloc(64 * 64 * 9);
  float* wt_d3   = alloc(64 * 64 * 9);
  float* wt_dc   = alloc(64 * 64 * 9);
  float* wt_f23  = alloc(27 * 54);
  float* wt_f12  = alloc(27 * 54);
  float* wt_a23  = alloc(64 * 128);
  float* wt_a12  = alloc(64 * 128);
  float* wt5_om1 = alloc(27 * 128 * 25);
  float* wt5_om2 = alloc(27 * 128 * 25);
  float* wt5_om3 = alloc(27 * 128 * 25);
  float* wt5_omc = alloc(27 * 128 * 25);
  if (ws_size < off * sizeof(float)) return;  // workspace too small: bail out

  float* a2_raw = fc2;     // fc2 dead after om2_raw conv
  float* a3     = fc3;     // fc3 dead after om3 conv
  float* a3_up  = om2_up;  // om2_up dead after om1

  float* out1 = out + (size_t)B * CC * HW1s;  // second output: [B][54][128][128]

  dim3 blk(256);
  int g;

  // ---- weight transposes (read-only inputs; run first) ----
  k_wtrans<<<(64 * 64 * 9 + 255) / 256, blk, 0, stream>>>(w_d1, wt_d1, 64, 64, 9);
  k_wtrans<<<(64 * 64 * 9 + 255) / 256, blk, 0, stream>>>(w_d2, wt_d2, 64, 64, 9);
  k_wtrans<<<(64 * 64 * 9 + 255) / 256, blk, 0, stream>>>(w_d3, wt_d3, 64, 64, 9);
  k_wtrans<<<(64 * 64 * 9 + 255) / 256, blk, 0, stream>>>(w_dc, wt_dc, 64, 64, 9);
  k_wtrans<<<(27 * 54 + 255) / 256, blk, 0, stream>>>(w_f23, wt_f23, 27, 54, 1);
  k_wtrans<<<(27 * 54 + 255) / 256, blk, 0, stream>>>(w_f12, wt_f12, 27, 54, 1);
  k_wtrans<<<(64 * 128 + 255) / 256, blk, 0, stream>>>(w_a23, wt_a23, 64, 128, 1);
  k_wtrans<<<(64 * 128 + 255) / 256, blk, 0, stream>>>(w_a12, wt_a12, 64, 128, 1);
  g = (27 * 128 * 25 + 255) / 256;
  k_wt5<<<g, blk, 0, stream>>>(w_om1, wt5_om1);
  k_wt5<<<g, blk, 0, stream>>>(w_om2, wt5_om2);
  k_wt5<<<g, blk, 0, stream>>>(w_om3, wt5_om3);
  k_wt5<<<g, blk, 0, stream>>>(w_omc, wt5_omc);

  // ---- pyramid downsample ----
  g = ((int)((size_t)B * CC * HW2s) + 255) / 256;
  k_down<<<g, blk, 0, stream>>>(feat_c, fc2, B * CC, H1, W1);
  k_down<<<g, blk, 0, stream>>>(feat_n, fn2, B * CC, H1, W1);
  g = ((int)((size_t)B * CC * HW3s) + 255) / 256;
  k_down<<<g, blk, 0, stream>>>(fc2, fc3, B * CC, H2, W2);
  k_down<<<g, blk, 0, stream>>>(fn2, fn3, B * CC, H2, W2);

  // ---- offset/mask branch ----
  k_conv5<<<B * (H3 / 16) * (W3 / 16), blk, 0, stream>>>(
      fc3, fn3, wt5_om3, b_om3, om3, H3, W3, 27LL * HW3s, 0LL);
  k_conv5<<<B * (H2 / 16) * (W2 / 16), blk, 0, stream>>>(
      fc2, fn2, wt5_om2, b_om2, om2_raw, H2, W2, 27LL * HW2s, 0LL);
  g = ((int)((size_t)B * 27 * HW2s) + 255) / 256;
  k_up<<<g, blk, 0, stream>>>(om3, om3_up, B * 27, H3, W3);
  {
    dim3 gg(HW2s / 256, B);
    k_conv1x1<27, 27, 27><<<gg, blk, 0, stream>>>(
        om2_raw, om3_up, wt_f23, b_f23, om2, HW2s, 27LL * HW2s, 0LL);
  }
  k_conv5<<<B * (H1 / 16) * (W1 / 16), blk, 0, stream>>>(
      feat_c, feat_n, wt5_om1, b_om1, om1_raw, H1, W1, 27LL * HW1s, 0LL);
  g = ((int)((size_t)B * 27 * HW1s) + 255) / 256;
  k_up<<<g, blk, 0, stream>>>(om2, om2_up, B * 27, H2, W2);
  {
    dim3 gg(HW1s / 256, B);  // om1 -> d_out second output, channels 0..26
    k_conv1x1<27, 27, 27><<<gg, blk, 0, stream>>>(
        om1_raw, om2_up, wt_f12, b_f12, out1, HW1s, 54LL * HW1s, 0LL);
  }

  // ---- aligned-feature branch ----
  {
    dim3 gg(HW3s / 256, B);
    k_dcn<64, 64><<<gg, blk, 0, stream>>>(
        fn3, om3, wt_d3, b_d3, a3, H3, W3, 27LL * HW3s, 64LL * HW3s, 0LL);
  }
  {
    dim3 gg(HW2s / 256, B);
    k_dcn<64, 64><<<gg, blk, 0, stream>>>(
        fn2, om2, wt_d2, b_d2, a2_raw, H2, W2, 27LL * HW2s, 64LL * HW2s, 0LL);
  }
  g = ((int)((size_t)B * CC * HW2s) + 255) / 256;
  k_up<<<g, blk, 0, stream>>>(a3, a3_up, B * CC, H3, W3);
  {
    dim3 gg(HW2s / 256, B);
    k_conv1x1<64, 64, 64><<<gg, blk, 0, stream>>>(
        a2_raw, a3_up, wt_a23, b_a23, a2, HW2s, 64LL * HW2s, 0LL);
  }
  {
    dim3 gg(HW1s / 256, B);  // om1 read back from d_out (channels 0..26 of [54])
    k_dcn<64, 64><<<gg, blk, 0, stream>>>(
        feat_n, out1, wt_d1, b_d1, a1_raw, H1, W1, 54LL * HW1s, 64LL * HW1s, 0LL);
  }
  g = ((int)((size_t)B * CC * HW1s) + 255) / 256;
  k_up<<<g, blk, 0, stream>>>(a2, a2_up, B * CC, H2, W2);
  {
    dim3 gg(HW1s / 256, B);
    k_conv1x1<64, 64, 64><<<gg, blk, 0, stream>>>(
        a1_raw, a2_up, wt_a12, b_a12, a1, HW1s, 64LL * HW1s, 0LL);
  }

  // ---- final: omc (-> d_out channels 27..53 of output 1), then ac ----
  k_conv5<<<B * (H1 / 16) * (W1 / 16), blk, 0, stream>>>(
      feat_c, a1, wt5_omc, b_omc, out1, H1, W1, 54LL * HW1s, 27LL * HW1s);
  {
    dim3 gg(HW1s / 256, B);
    k_dcn<64, 64><<<gg, blk, 0, stream>>>(
        a1, out1 + 27LL * HW1s, wt_dc, b_dc, out, H1, W1,
        54LL * HW1s, 64LL * HW1s, 0LL);
  }
}

// Round 9
// 1722.108 us; speedup vs baseline: 3.9239x; 2.3512x over previous
//
#include <hip/hip_runtime.h>
#include <cstdint>
#include <cstddef>

// =====================================================================
// PyrDCNAlign — r8: conv5 -> bf16 MFMA implicit GEMM (tap-wise accum).
//   r8 counters: conv5 LDS-pipe-bound (22.4k ds_read_b128/thread for
//   weight broadcast; VALUBusy 29%, MfmaUtil 0). Fix: 16x16x32 bf16
//   MFMA, channels-last bf16 LDS act tile (B-frag = 1 ds_read_b128),
//   A-frags pre-baked per-lane in global. DCN/1x1/resize unchanged.
// =====================================================================

#define BB 8
#define CC 64

typedef __attribute__((ext_vector_type(8))) short bf16x8;
typedef __attribute__((ext_vector_type(4))) float f32x4;

__device__ inline unsigned short f2bf(float f) {
  unsigned int u = __float_as_uint(f);
  return (unsigned short)((u + 0x7FFFu + ((u >> 16) & 1u)) >> 16);
}

// ---------------- bicubic resize, scale 0.5 (fixed weights) ----------------
__global__ __launch_bounds__(256) void k_down(const float* __restrict__ in,
                                              float* __restrict__ out,
                                              int BC, int Hin, int Win) {
  const int Ho = Hin >> 1, Wo = Win >> 1;
  const float W4[4] = {-0.09375f, 0.59375f, 0.59375f, -0.09375f};
  int total = BC * Ho * Wo;
  for (int idx = blockIdx.x * 256 + threadIdx.x; idx < total; idx += gridDim.x * 256) {
    int x = idx % Wo;
    int y = (idx / Wo) % Ho;
    int bc = idx / (Wo * Ho);
    const float* src = in + (size_t)bc * Hin * Win;
    float s = 0.f;
#pragma unroll
    for (int i = 0; i < 4; ++i) {
      int yy = 2 * y - 1 + i;
      yy = min(max(yy, 0), Hin - 1);
      const float* row = src + (size_t)yy * Win;
      float rs = 0.f;
#pragma unroll
      for (int j = 0; j < 4; ++j) {
        int xx = 2 * x - 1 + j;
        xx = min(max(xx, 0), Win - 1);
        rs = fmaf(W4[j], row[xx], rs);
      }
      s = fmaf(W4[i], rs, s);
    }
    out[idx] = s;
  }
}

// ---------------- bicubic resize, scale 2.0 (fixed weights by parity) -------
__global__ __launch_bounds__(256) void k_up(const float* __restrict__ in,
                                            float* __restrict__ out,
                                            int BC, int Hin, int Win) {
  const int Ho = Hin << 1, Wo = Win << 1;
  const float WE[4] = {-0.03515625f, 0.26171875f, 0.87890625f, -0.10546875f};
  int total = BC * Ho * Wo;
  for (int idx = blockIdx.x * 256 + threadIdx.x; idx < total; idx += gridDim.x * 256) {
    int x = idx % Wo;
    int y = (idx / Wo) % Ho;
    int bc = idx / (Wo * Ho);
    const float* src = in + (size_t)bc * Hin * Win;
    int fy = (y & 1) ? (y >> 1) : (y >> 1) - 1;
    int fx = (x & 1) ? (x >> 1) : (x >> 1) - 1;
    float s = 0.f;
#pragma unroll
    for (int i = 0; i < 4; ++i) {
      float wy = (y & 1) ? WE[3 - i] : WE[i];
      int yy = min(max(fy - 1 + i, 0), Hin - 1);
      const float* row = src + (size_t)yy * Win;
      float rs = 0.f;
#pragma unroll
      for (int j = 0; j < 4; ++j) {
        float wx = (x & 1) ? WE[3 - j] : WE[j];
        int xx = min(max(fx - 1 + j, 0), Win - 1);
        rs = fmaf(wx, row[xx], rs);
      }
      s = fmaf(wy, rs, s);
    }
    out[idx] = s;
  }
}

// ---------------- weight transpose: [O][Ci][K] -> [K][Ci][O] ----------------
__global__ __launch_bounds__(256) void k_wtrans(const float* __restrict__ in,
                                                float* __restrict__ out,
                                                int COUT, int CIN, int K) {
  int total = COUT * CIN * K;
  int i = blockIdx.x * 256 + threadIdx.x;
  if (i >= total) return;
  int k = i % K;
  int c = (i / K) % CIN;
  int oc = i / (K * CIN);
  out[((size_t)k * CIN + c) * COUT + oc] = in[i];
}

// ------- conv5 MFMA weight prep: w[27][128][25] -> per-lane A-frags --------
// wmfa[(step*2+m)*512 + lane*8 + j], step = ccg*25+tap:
//   oc = m*16 + (lane&15); cc = ccg*32 + (lane>>4)*8 + j; bf16(w[oc][cc][tap])
__global__ __launch_bounds__(256) void k_wmfa(const float* __restrict__ w,
                                              unsigned short* __restrict__ o) {
  int i = blockIdx.x * 256 + threadIdx.x;
  if (i >= 100 * 1024) return;
  int j = i & 7;
  int lane = (i >> 3) & 63;
  int sm = i >> 9;           // step*2 + m
  int m = sm & 1;
  int step = sm >> 1;        // ccg*25 + tap
  int ccg = step / 25, tap = step - ccg * 25;
  int oc = m * 16 + (lane & 15);
  int cc = ccg * 32 + (lane >> 4) * 8 + j;
  float v = (oc < 27) ? w[((size_t)oc * 128 + cc) * 25 + tap] : 0.f;
  o[i] = f2bf(v);
}

// ---------------- 5x5 conv via bf16 MFMA, Cin=64+64, pad=2 ------------------
// Block 256thr/4 waves; output tile 32oc(27) x (16w x 8h) px.
// LDS: act[pos(20x12)][136ch] bf16 channels-last; staged once, no further
// barriers. Wave w: px rows 2w,2w+1; 100 K-steps (4ccg x 25tap) x 4 MFMA.
__global__ __launch_bounds__(256) void k_conv5m(
    const float* __restrict__ inA, const float* __restrict__ inB,
    const unsigned short* __restrict__ wmfa, const float* __restrict__ bias,
    float* __restrict__ out, int H, int W,
    long long obatch, long long ochoff) {
  __shared__ unsigned short act[240 * 136];  // 65,280 B
  const int tilesX = W >> 4;
  const int tilesY = H >> 3;
  const int tpb = tilesX * tilesY;
  const int b = blockIdx.x / tpb;
  const int t = blockIdx.x - b * tpb;
  const int ty0 = (t / tilesX) << 3;
  const int tx0 = (t % tilesX) << 4;
  const int HW = H * W;
  const int lane = threadIdx.x & 63;
  const int wv = threadIdx.x >> 6;

  // stage halo 20x12 x 128ch, bf16, zero OOB (conv zero-padding)
  for (int i = threadIdx.x; i < 240 * 128; i += 256) {
    int c = i / 240;
    int pos = i - c * 240;
    int hy = pos / 20, hx = pos - hy * 20;
    int gy = ty0 + hy - 2, gx = tx0 + hx - 2;
    const float* src = (c < 64) ? inA + ((size_t)b * 64 + c) * HW
                                : inB + ((size_t)b * 64 + (c - 64)) * HW;
    float v = 0.f;
    if (gy >= 0 && gy < H && gx >= 0 && gx < W) v = src[(size_t)gy * W + gx];
    act[pos * 136 + c] = f2bf(v);
  }
  __syncthreads();

  const int pxx = lane & 15;
  const int kg = lane >> 4;

  f32x4 acc[2][2];
#pragma unroll
  for (int m = 0; m < 2; ++m)
#pragma unroll
    for (int r = 0; r < 2; ++r)
#pragma unroll
      for (int q = 0; q < 4; ++q) {
        int oc = m * 16 + kg * 4 + q;
        acc[m][r][q] = (oc < 27) ? bias[oc] : 0.f;
      }

  const int rowbase = (2 * wv) * 20 + pxx;     // halo pos of out row 0, this lane
  const int cbase = kg * 8;

  for (int ccg = 0; ccg < 4; ++ccg) {
    const int coff = ccg * 32 + cbase;
#pragma unroll
    for (int tap = 0; tap < 25; ++tap) {
      const int step = ccg * 25 + tap;
      const bf16x8* wp = (const bf16x8*)(wmfa + (size_t)step * 1024);
      bf16x8 a0 = wp[lane];
      bf16x8 a1 = wp[64 + lane];
      const int dy = tap / 5, dx = tap - 5 * (tap / 5);
      const int base0 = (rowbase + dy * 20 + dx) * 136 + coff;
      bf16x8 b0 = *(const bf16x8*)(act + base0);
      bf16x8 b1 = *(const bf16x8*)(act + base0 + 20 * 136);
      acc[0][0] = __builtin_amdgcn_mfma_f32_16x16x32_bf16(a0, b0, acc[0][0], 0, 0, 0);
      acc[0][1] = __builtin_amdgcn_mfma_f32_16x16x32_bf16(a0, b1, acc[0][1], 0, 0, 0);
      acc[1][0] = __builtin_amdgcn_mfma_f32_16x16x32_bf16(a1, b0, acc[1][0], 0, 0, 0);
      acc[1][1] = __builtin_amdgcn_mfma_f32_16x16x32_bf16(a1, b1, acc[1][1], 0, 0, 0);
    }
  }

  // C/D: col=lane&15 (px), row=(lane>>4)*4+reg (oc_local)
#pragma unroll
  for (int m = 0; m < 2; ++m)
#pragma unroll
    for (int r = 0; r < 2; ++r) {
      int py = 2 * wv + r;
      float* op = out + (size_t)b * obatch + ochoff + (size_t)(ty0 + py) * W + tx0 + pxx;
#pragma unroll
      for (int q = 0; q < 4; ++q) {
        int oc = m * 16 + kg * 4 + q;
        if (oc < 27) op[(size_t)oc * HW] = acc[m][r][q];
      }
    }
}

// ---------------- 1x1 conv over concat(inA[CINA], inB[CINB]) ----------------
template <int CINA, int CINB, int COUT>
__global__ __launch_bounds__(256) void k_conv1x1(
    const float* __restrict__ inA, const float* __restrict__ inB,
    const float* __restrict__ wT, const float* __restrict__ bias,
    float* __restrict__ out, int HW, long long obatch, long long ochoff) {
  const int b = blockIdx.y;
  const int p = blockIdx.x * 256 + threadIdx.x;
  if (p >= HW) return;
  float acc[COUT];
#pragma unroll
  for (int i = 0; i < COUT; ++i) acc[i] = bias[i];
  const float* pa = inA + (size_t)b * CINA * HW + p;
  for (int c = 0; c < CINA; ++c) {
    float v = pa[(size_t)c * HW];
    const float* w = wT + (size_t)c * COUT;
#pragma unroll
    for (int oc = 0; oc < COUT; ++oc) acc[oc] = fmaf(w[oc], v, acc[oc]);
  }
  const float* pb = inB + (size_t)b * CINB * HW + p;
  for (int c = 0; c < CINB; ++c) {
    float v = pb[(size_t)c * HW];
    const float* w = wT + (size_t)(CINA + c) * COUT;
#pragma unroll
    for (int oc = 0; oc < COUT; ++oc) acc[oc] = fmaf(w[oc], v, acc[oc]);
  }
  float* op = out + (size_t)b * obatch + ochoff + p;
#pragma unroll
  for (int oc = 0; oc < COUT; ++oc) op[(size_t)oc * HW] = acc[oc];
}

// ---------------- modulated deformable conv 3x3, dg=1 ----------------------
template <int CIN, int COUT>
__global__ __launch_bounds__(256) void k_dcn(
    const float* __restrict__ fn, const float* __restrict__ om,
    const float* __restrict__ wT, const float* __restrict__ bias,
    float* __restrict__ out, int H, int W,
    long long omBatch, long long outBatch, long long outChOff) {
  const int b = blockIdx.y;
  const int p = blockIdx.x * 256 + threadIdx.x;
  const int HW = H * W;
  if (p >= HW) return;
  const int y = p / W;
  const int x = p - y * W;
  const float* omb = om + (size_t)b * omBatch;
  const float* fnb = fn + (size_t)b * CIN * HW;

  float acc[COUT];
#pragma unroll
  for (int i = 0; i < COUT; ++i) acc[i] = bias[i];

  for (int k = 0; k < 9; ++k) {
    float dy = omb[(size_t)(2 * k) * HW + p];
    float dx = omb[(size_t)(2 * k + 1) * HW + p];
    float ml = omb[(size_t)(18 + k) * HW + p];
    float m = 1.f / (1.f + __expf(-ml));
    float py = (float)(y + (k / 3) - 1) + dy;
    float px = (float)(x + (k % 3) - 1) + dx;
    float y0f = floorf(py), x0f = floorf(px);
    float ly = py - y0f, lx = px - x0f;
    int y0 = (int)y0f, x0 = (int)x0f;
    int y1 = y0 + 1, x1 = x0 + 1;
    float w00 = (1.f - ly) * (1.f - lx) * m;
    float w01 = (1.f - ly) * lx * m;
    float w10 = ly * (1.f - lx) * m;
    float w11 = ly * lx * m;
    bool vy0 = ((unsigned)y0 < (unsigned)H);
    bool vy1 = ((unsigned)y1 < (unsigned)H);
    bool vx0 = ((unsigned)x0 < (unsigned)W);
    bool vx1 = ((unsigned)x1 < (unsigned)W);
    if (!(vy0 && vx0)) w00 = 0.f;
    if (!(vy0 && vx1)) w01 = 0.f;
    if (!(vy1 && vx0)) w10 = 0.f;
    if (!(vy1 && vx1)) w11 = 0.f;
    int cy0 = min(max(y0, 0), H - 1), cy1 = min(max(y1, 0), H - 1);
    int cx0 = min(max(x0, 0), W - 1), cx1 = min(max(x1, 0), W - 1);
    int o00 = cy0 * W + cx0, o01 = cy0 * W + cx1;
    int o10 = cy1 * W + cx0, o11 = cy1 * W + cx1;
    for (int c = 0; c < CIN; ++c) {
      const float* f = fnb + (size_t)c * HW;
      float val = w00 * f[o00] + w01 * f[o01] + w10 * f[o10] + w11 * f[o11];
      const float* w = wT + ((size_t)k * CIN + c) * COUT;
#pragma unroll
      for (int oc = 0; oc < COUT; ++oc) acc[oc] = fmaf(w[oc], val, acc[oc]);
    }
  }
  float* op = out + (size_t)b * outBatch + outChOff + p;
#pragma unroll
  for (int oc = 0; oc < COUT; ++oc) op[(size_t)oc * HW] = acc[oc];
}

// =====================================================================
extern "C" void kernel_launch(void* const* d_in, const int* in_sizes, int n_in,
                              void* d_out, int out_size, void* d_ws, size_t ws_size,
                              hipStream_t stream) {
  const float* feat_c = (const float*)d_in[0];
  const float* feat_n = (const float*)d_in[1];
  const float* w_om1 = (const float*)d_in[2];  const float* b_om1 = (const float*)d_in[3];
  const float* w_om2 = (const float*)d_in[4];  const float* b_om2 = (const float*)d_in[5];
  const float* w_om3 = (const float*)d_in[6];  const float* b_om3 = (const float*)d_in[7];
  const float* w_omc = (const float*)d_in[8];  const float* b_omc = (const float*)d_in[9];
  const float* w_f23 = (const float*)d_in[10]; const float* b_f23 = (const float*)d_in[11];
  const float* w_f12 = (const float*)d_in[12]; const float* b_f12 = (const float*)d_in[13];
  const float* w_a23 = (const float*)d_in[14]; const float* b_a23 = (const float*)d_in[15];
  const float* w_a12 = (const float*)d_in[16]; const float* b_a12 = (const float*)d_in[17];
  const float* w_d1 = (const float*)d_in[18];  const float* b_d1 = (const float*)d_in[19];
  const float* w_d2 = (const float*)d_in[20];  const float* b_d2 = (const float*)d_in[21];
  const float* w_d3 = (const float*)d_in[22];  const float* b_d3 = (const float*)d_in[23];
  const float* w_dc = (const float*)d_in[24];  const float* b_dc = (const float*)d_in[25];

  float* out = (float*)d_out;
  float* ws = (float*)d_ws;

  const int H1 = 128, W1 = 128, HW1s = 16384;
  const int H2 = 64,  W2 = 64,  HW2s = 4096;
  const int H3 = 32,  W3 = 32,  HW3s = 1024;
  const int B = BB;

  // ---- workspace arena (fp32 elements), lifetime-checked aliases ----
  size_t off = 0;
  auto alloc = [&](size_t n) { float* p = ws + off; off += n; return p; };
  float* fc2     = alloc((size_t)B * CC * HW2s);   // aliased later: a2_raw
  float* fn2     = alloc((size_t)B * CC * HW2s);
  float* fc3     = alloc((size_t)B * CC * HW3s);   // aliased later: a3
  float* fn3     = alloc((size_t)B * CC * HW3s);
  float* om3     = alloc((size_t)B * 27 * HW3s);
  float* om2_raw = alloc((size_t)B * 27 * HW2s);
  float* om3_up  = alloc((size_t)B * 27 * HW2s);
  float* om2     = alloc((size_t)B * 27 * HW2s);
  float* om1_raw = alloc((size_t)B * 27 * HW1s);
  float* om2_up  = alloc((size_t)B * 27 * HW1s);   // aliased later: a3_up
  float* a2      = alloc((size_t)B * CC * HW2s);
  float* a1_raw  = alloc((size_t)B * CC * HW1s);
  float* a2_up   = alloc((size_t)B * CC * HW1s);
  float* a1      = alloc((size_t)B * CC * HW1s);
  float* wt_d1   = alloc(64 * 64 * 9);
  float* wt_d2   = alloc(64 * 64 * 9);
  float* wt_d3   = alloc(64 * 64 * 9);
  float* wt_dc   = alloc(64 * 64 * 9);
  float* wt_f23  = alloc(27 * 54);
  float* wt_f12  = alloc(27 * 54);
  float* wt_a23  = alloc(64 * 128);
  float* wt_a12  = alloc(64 * 128);
  // MFMA A-frag buffers: 102,400 ushort = 51,200 fp32 each
  unsigned short* wmfa_om1 = (unsigned short*)alloc(51200);
  unsigned short* wmfa_om2 = (unsigned short*)alloc(51200);
  unsigned short* wmfa_om3 = (unsigned short*)alloc(51200);
  unsigned short* wmfa_omc = (unsigned short*)alloc(51200);
  if (ws_size < off * sizeof(float)) return;  // workspace too small: bail out

  float* a2_raw = fc2;     // fc2 dead after om2_raw conv
  float* a3     = fc3;     // fc3 dead after om3 conv
  float* a3_up  = om2_up;  // om2_up dead after om1

  float* out1 = out + (size_t)B * CC * HW1s;  // second output: [B][54][128][128]

  dim3 blk(256);
  int g;

  // ---- weight preps (read-only inputs; run first) ----
  k_wtrans<<<(64 * 64 * 9 + 255) / 256, blk, 0, stream>>>(w_d1, wt_d1, 64, 64, 9);
  k_wtrans<<<(64 * 64 * 9 + 255) / 256, blk, 0, stream>>>(w_d2, wt_d2, 64, 64, 9);
  k_wtrans<<<(64 * 64 * 9 + 255) / 256, blk, 0, stream>>>(w_d3, wt_d3, 64, 64, 9);
  k_wtrans<<<(64 * 64 * 9 + 255) / 256, blk, 0, stream>>>(w_dc, wt_dc, 64, 64, 9);
  k_wtrans<<<(27 * 54 + 255) / 256, blk, 0, stream>>>(w_f23, wt_f23, 27, 54, 1);
  k_wtrans<<<(27 * 54 + 255) / 256, blk, 0, stream>>>(w_f12, wt_f12, 27, 54, 1);
  k_wtrans<<<(64 * 128 + 255) / 256, blk, 0, stream>>>(w_a23, wt_a23, 64, 128, 1);
  k_wtrans<<<(64 * 128 + 255) / 256, blk, 0, stream>>>(w_a12, wt_a12, 64, 128, 1);
  g = (100 * 1024 + 255) / 256;
  k_wmfa<<<g, blk, 0, stream>>>(w_om1, wmfa_om1);
  k_wmfa<<<g, blk, 0, stream>>>(w_om2, wmfa_om2);
  k_wmfa<<<g, blk, 0, stream>>>(w_om3, wmfa_om3);
  k_wmfa<<<g, blk, 0, stream>>>(w_omc, wmfa_omc);

  // ---- pyramid downsample ----
  g = ((int)((size_t)B * CC * HW2s) + 255) / 256;
  k_down<<<g, blk, 0, stream>>>(feat_c, fc2, B * CC, H1, W1);
  k_down<<<g, blk, 0, stream>>>(feat_n, fn2, B * CC, H1, W1);
  g = ((int)((size_t)B * CC * HW3s) + 255) / 256;
  k_down<<<g, blk, 0, stream>>>(fc2, fc3, B * CC, H2, W2);
  k_down<<<g, blk, 0, stream>>>(fn2, fn3, B * CC, H2, W2);

  // ---- offset/mask branch ----
  k_conv5m<<<B * (W3 / 16) * (H3 / 8), blk, 0, stream>>>(
      fc3, fn3, wmfa_om3, b_om3, om3, H3, W3, 27LL * HW3s, 0LL);
  k_conv5m<<<B * (W2 / 16) * (H2 / 8), blk, 0, stream>>>(
      fc2, fn2, wmfa_om2, b_om2, om2_raw, H2, W2, 27LL * HW2s, 0LL);
  g = ((int)((size_t)B * 27 * HW2s) + 255) / 256;
  k_up<<<g, blk, 0, stream>>>(om3, om3_up, B * 27, H3, W3);
  {
    dim3 gg(HW2s / 256, B);
    k_conv1x1<27, 27, 27><<<gg, blk, 0, stream>>>(
        om2_raw, om3_up, wt_f23, b_f23, om2, HW2s, 27LL * HW2s, 0LL);
  }
  k_conv5m<<<B * (W1 / 16) * (H1 / 8), blk, 0, stream>>>(
      feat_c, feat_n, wmfa_om1, b_om1, om1_raw, H1, W1, 27LL * HW1s, 0LL);
  g = ((int)((size_t)B * 27 * HW1s) + 255) / 256;
  k_up<<<g, blk, 0, stream>>>(om2, om2_up, B * 27, H2, W2);
  {
    dim3 gg(HW1s / 256, B);  // om1 -> d_out second output, channels 0..26
    k_conv1x1<27, 27, 27><<<gg, blk, 0, stream>>>(
        om1_raw, om2_up, wt_f12, b_f12, out1, HW1s, 54LL * HW1s, 0LL);
  }

  // ---- aligned-feature branch ----
  {
    dim3 gg(HW3s / 256, B);
    k_dcn<64, 64><<<gg, blk, 0, stream>>>(
        fn3, om3, wt_d3, b_d3, a3, H3, W3, 27LL * HW3s, 64LL * HW3s, 0LL);
  }
  {
    dim3 gg(HW2s / 256, B);
    k_dcn<64, 64><<<gg, blk, 0, stream>>>(
        fn2, om2, wt_d2, b_d2, a2_raw, H2, W2, 27LL * HW2s, 64LL * HW2s, 0LL);
  }
  g = ((int)((size_t)B * CC * HW2s) + 255) / 256;
  k_up<<<g, blk, 0, stream>>>(a3, a3_up, B * CC, H3, W3);
  {
    dim3 gg(HW2s / 256, B);
    k_conv1x1<64, 64, 64><<<gg, blk, 0, stream>>>(
        a2_raw, a3_up, wt_a23, b_a23, a2, HW2s, 64LL * HW2s, 0LL);
  }
  {
    dim3 gg(HW1s / 256, B);  // om1 read back from d_out (channels 0..26 of [54])
    k_dcn<64, 64><<<gg, blk, 0, stream>>>(
        feat_n, out1, wt_d1, b_d1, a1_raw, H1, W1, 54LL * HW1s, 64LL * HW1s, 0LL);
  }
  g = ((int)((size_t)B * CC * HW1s) + 255) / 256;
  k_up<<<g, blk, 0, stream>>>(a2, a2_up, B * CC, H2, W2);
  {
    dim3 gg(HW1s / 256, B);
    k_conv1x1<64, 64, 64><<<gg, blk, 0, stream>>>(
        a1_raw, a2_up, wt_a12, b_a12, a1, HW1s, 64LL * HW1s, 0LL);
  }

  // ---- final: omc (-> d_out channels 27..53 of output 1), then ac ----
  k_conv5m<<<B * (W1 / 16) * (H1 / 8), blk, 0, stream>>>(
      feat_c, a1, wmfa_omc, b_omc, out1, H1, W1, 54LL * HW1s, 27LL * HW1s);
  {
    dim3 gg(HW1s / 256, B);
    k_dcn<64, 64><<<gg, blk, 0, stream>>>(
        a1, out1 + 27LL * HW1s, wt_dc, b_dc, out, H1, W1,
        54LL * HW1s, 64LL * HW1s, 0LL);
  }
}

// Round 10
// 1106.246 us; speedup vs baseline: 6.1084x; 1.5567x over previous
//
#include <hip/hip_runtime.h>
#include <cstdint>
#include <cstddef>

// =====================================================================
// PyrDCNAlign — r9: DCN -> bf16 MFMA + channels-last gather.
//   r9 counters: k_dcn L1 260us, FETCH 471MB (~9x over-fetch), MfmaUtil 0.
//   Fix: fnT channels-last bf16 [B][HW][64] (corner gather = 16B vector),
//   per-tap 64x64 GEMM on MFMA (val staged in LDS), A-frags pre-baked.
//   conv5m/conv1x1/resize unchanged from r9 (passing, absmax 0.0156).
// =====================================================================

#define BB 8
#define CC 64

typedef __attribute__((ext_vector_type(8))) short bf16x8;
typedef __attribute__((ext_vector_type(4))) float f32x4;

__device__ inline unsigned short f2bf(float f) {
  unsigned int u = __float_as_uint(f);
  return (unsigned short)((u + 0x7FFFu + ((u >> 16) & 1u)) >> 16);
}
__device__ inline float bf2f(short s) {
  return __uint_as_float(((unsigned int)(unsigned short)s) << 16);
}

// ---------------- bicubic resize, scale 0.5 (fixed weights) ----------------
__global__ __launch_bounds__(256) void k_down(const float* __restrict__ in,
                                              float* __restrict__ out,
                                              int BC, int Hin, int Win) {
  const int Ho = Hin >> 1, Wo = Win >> 1;
  const float W4[4] = {-0.09375f, 0.59375f, 0.59375f, -0.09375f};
  int total = BC * Ho * Wo;
  for (int idx = blockIdx.x * 256 + threadIdx.x; idx < total; idx += gridDim.x * 256) {
    int x = idx % Wo;
    int y = (idx / Wo) % Ho;
    int bc = idx / (Wo * Ho);
    const float* src = in + (size_t)bc * Hin * Win;
    float s = 0.f;
#pragma unroll
    for (int i = 0; i < 4; ++i) {
      int yy = 2 * y - 1 + i;
      yy = min(max(yy, 0), Hin - 1);
      const float* row = src + (size_t)yy * Win;
      float rs = 0.f;
#pragma unroll
      for (int j = 0; j < 4; ++j) {
        int xx = 2 * x - 1 + j;
        xx = min(max(xx, 0), Win - 1);
        rs = fmaf(W4[j], row[xx], rs);
      }
      s = fmaf(W4[i], rs, s);
    }
    out[idx] = s;
  }
}

// ---------------- bicubic resize, scale 2.0 (fixed weights by parity) -------
__global__ __launch_bounds__(256) void k_up(const float* __restrict__ in,
                                            float* __restrict__ out,
                                            int BC, int Hin, int Win) {
  const int Ho = Hin << 1, Wo = Win << 1;
  const float WE[4] = {-0.03515625f, 0.26171875f, 0.87890625f, -0.10546875f};
  int total = BC * Ho * Wo;
  for (int idx = blockIdx.x * 256 + threadIdx.x; idx < total; idx += gridDim.x * 256) {
    int x = idx % Wo;
    int y = (idx / Wo) % Ho;
    int bc = idx / (Wo * Ho);
    const float* src = in + (size_t)bc * Hin * Win;
    int fy = (y & 1) ? (y >> 1) : (y >> 1) - 1;
    int fx = (x & 1) ? (x >> 1) : (x >> 1) - 1;
    float s = 0.f;
#pragma unroll
    for (int i = 0; i < 4; ++i) {
      float wy = (y & 1) ? WE[3 - i] : WE[i];
      int yy = min(max(fy - 1 + i, 0), Hin - 1);
      const float* row = src + (size_t)yy * Win;
      float rs = 0.f;
#pragma unroll
      for (int j = 0; j < 4; ++j) {
        float wx = (x & 1) ? WE[3 - j] : WE[j];
        int xx = min(max(fx - 1 + j, 0), Win - 1);
        rs = fmaf(wx, row[xx], rs);
      }
      s = fmaf(wy, rs, s);
    }
    out[idx] = s;
  }
}

// ---------------- weight transpose: [O][Ci][K] -> [K][Ci][O] ----------------
__global__ __launch_bounds__(256) void k_wtrans(const float* __restrict__ in,
                                                float* __restrict__ out,
                                                int COUT, int CIN, int K) {
  int total = COUT * CIN * K;
  int i = blockIdx.x * 256 + threadIdx.x;
  if (i >= total) return;
  int k = i % K;
  int c = (i / K) % CIN;
  int oc = i / (K * CIN);
  out[((size_t)k * CIN + c) * COUT + oc] = in[i];
}

// ------- conv5 MFMA weight prep: w[27][128][25] -> per-lane A-frags --------
__global__ __launch_bounds__(256) void k_wmfa(const float* __restrict__ w,
                                              unsigned short* __restrict__ o) {
  int i = blockIdx.x * 256 + threadIdx.x;
  if (i >= 100 * 1024) return;
  int j = i & 7;
  int lane = (i >> 3) & 63;
  int sm = i >> 9;           // step*2 + m
  int m = sm & 1;
  int step = sm >> 1;        // ccg*25 + tap
  int ccg = step / 25, tap = step - ccg * 25;
  int oc = m * 16 + (lane & 15);
  int cc = ccg * 32 + (lane >> 4) * 8 + j;
  float v = (oc < 27) ? w[((size_t)oc * 128 + cc) * 25 + tap] : 0.f;
  o[i] = f2bf(v);
}

// ------- DCN MFMA weight prep: w[64][64][9] -> per-lane A-frags ------------
// o[((step*4+m)*64 + lane)*8 + j], step = k*2+ks:
//   oc = m*16+(lane&15); c = ks*32+(lane>>4)*8+j; bf16(w[oc][c][k])
__global__ __launch_bounds__(256) void k_wmfd(const float* __restrict__ w,
                                              unsigned short* __restrict__ o) {
  int i = blockIdx.x * 256 + threadIdx.x;
  if (i >= 18 * 4 * 512) return;
  int j = i & 7;
  int lane = (i >> 3) & 63;
  int m = (i >> 9) & 3;
  int step = i >> 11;        // k*2 + ks
  int ks = step & 1, k = step >> 1;
  int oc = m * 16 + (lane & 15);
  int c = ks * 32 + (lane >> 4) * 8 + j;
  o[i] = f2bf(w[((size_t)oc * 64 + c) * 9 + k]);
}

// ------- channels-last bf16: in[B][64][HW] f32 -> o[B][HW][64] bf16 --------
__global__ __launch_bounds__(256) void k_cl(const float* __restrict__ in,
                                            unsigned short* __restrict__ o,
                                            int HW, int total) {
  int i = blockIdx.x * 256 + threadIdx.x;   // i = (b*HW + hw)*8 + cg
  if (i >= total) return;
  int cg = i & 7;
  int r = i >> 3;
  int hw = r % HW;
  int b = r / HW;
  const float* src = in + ((size_t)b * 64 + cg * 8) * HW + hw;
  bf16x8 v;
#pragma unroll
  for (int j = 0; j < 8; ++j) v[j] = (short)f2bf(src[(size_t)j * HW]);
  *(bf16x8*)(o + ((size_t)b * HW + hw) * 64 + cg * 8) = v;
}

// ---------------- 5x5 conv via bf16 MFMA, Cin=64+64, pad=2 ------------------
__global__ __launch_bounds__(256) void k_conv5m(
    const float* __restrict__ inA, const float* __restrict__ inB,
    const unsigned short* __restrict__ wmfa, const float* __restrict__ bias,
    float* __restrict__ out, int H, int W,
    long long obatch, long long ochoff) {
  __shared__ unsigned short act[240 * 136];  // 65,280 B
  const int tilesX = W >> 4;
  const int tilesY = H >> 3;
  const int tpb = tilesX * tilesY;
  const int b = blockIdx.x / tpb;
  const int t = blockIdx.x - b * tpb;
  const int ty0 = (t / tilesX) << 3;
  const int tx0 = (t % tilesX) << 4;
  const int HW = H * W;
  const int lane = threadIdx.x & 63;
  const int wv = threadIdx.x >> 6;

  for (int i = threadIdx.x; i < 240 * 128; i += 256) {
    int c = i / 240;
    int pos = i - c * 240;
    int hy = pos / 20, hx = pos - hy * 20;
    int gy = ty0 + hy - 2, gx = tx0 + hx - 2;
    const float* src = (c < 64) ? inA + ((size_t)b * 64 + c) * HW
                                : inB + ((size_t)b * 64 + (c - 64)) * HW;
    float v = 0.f;
    if (gy >= 0 && gy < H && gx >= 0 && gx < W) v = src[(size_t)gy * W + gx];
    act[pos * 136 + c] = f2bf(v);
  }
  __syncthreads();

  const int pxx = lane & 15;
  const int kg = lane >> 4;

  f32x4 acc[2][2];
#pragma unroll
  for (int m = 0; m < 2; ++m)
#pragma unroll
    for (int r = 0; r < 2; ++r)
#pragma unroll
      for (int q = 0; q < 4; ++q) {
        int oc = m * 16 + kg * 4 + q;
        acc[m][r][q] = (oc < 27) ? bias[oc] : 0.f;
      }

  const int rowbase = (2 * wv) * 20 + pxx;
  const int cbase = kg * 8;

  for (int ccg = 0; ccg < 4; ++ccg) {
    const int coff = ccg * 32 + cbase;
#pragma unroll
    for (int tap = 0; tap < 25; ++tap) {
      const int step = ccg * 25 + tap;
      const bf16x8* wp = (const bf16x8*)(wmfa + (size_t)step * 1024);
      bf16x8 a0 = wp[lane];
      bf16x8 a1 = wp[64 + lane];
      const int dy = tap / 5, dx = tap - 5 * (tap / 5);
      const int base0 = (rowbase + dy * 20 + dx) * 136 + coff;
      bf16x8 b0 = *(const bf16x8*)(act + base0);
      bf16x8 b1 = *(const bf16x8*)(act + base0 + 20 * 136);
      acc[0][0] = __builtin_amdgcn_mfma_f32_16x16x32_bf16(a0, b0, acc[0][0], 0, 0, 0);
      acc[0][1] = __builtin_amdgcn_mfma_f32_16x16x32_bf16(a0, b1, acc[0][1], 0, 0, 0);
      acc[1][0] = __builtin_amdgcn_mfma_f32_16x16x32_bf16(a1, b0, acc[1][0], 0, 0, 0);
      acc[1][1] = __builtin_amdgcn_mfma_f32_16x16x32_bf16(a1, b1, acc[1][1], 0, 0, 0);
    }
  }

#pragma unroll
  for (int m = 0; m < 2; ++m)
#pragma unroll
    for (int r = 0; r < 2; ++r) {
      int py = 2 * wv + r;
      float* op = out + (size_t)b * obatch + ochoff + (size_t)(ty0 + py) * W + tx0 + pxx;
#pragma unroll
      for (int q = 0; q < 4; ++q) {
        int oc = m * 16 + kg * 4 + q;
        if (oc < 27) op[(size_t)oc * HW] = acc[m][r][q];
      }
    }
}

// ---------------- modulated DCN 3x3 via bf16 MFMA ---------------------------
// Block: 64-px strip x 64 oc. fnT channels-last bf16 [B][HW][64].
// Per tap k: phase1 = bilinear gather -> val[64px][72c] LDS (bf16);
// phase2 = wave wv computes oc-tile wv via 2 K-steps x 4 px-tiles MFMA.
__global__ __launch_bounds__(256) void k_dcnm(
    const unsigned short* __restrict__ fnT, const float* __restrict__ om,
    const unsigned short* __restrict__ wf, const float* __restrict__ bias,
    float* __restrict__ out, int H, int W,
    long long omBatch, long long outBatch, long long outChOff) {
  __shared__ unsigned short val[64 * 72];  // 9216 B
  const int b = blockIdx.y;
  const int HW = H * W;
  const int px0 = blockIdx.x * 64;
  const int tid = threadIdx.x;
  const int lane = tid & 63;
  const int wv = tid >> 6;
  const int pl = lane;            // phase1: px local
  const int cq = wv;              // phase1: channel quad (16 ch)
  const int pxg = px0 + pl;
  const int y = pxg / W, x = pxg - y * W;
  const float* omb = om + (size_t)b * omBatch;
  const unsigned short* fb = fnT + (size_t)b * HW * 64;

  f32x4 acc[4];
#pragma unroll
  for (int q = 0; q < 4; ++q)
#pragma unroll
    for (int rg = 0; rg < 4; ++rg)
      acc[q][rg] = bias[wv * 16 + (lane >> 4) * 4 + rg];

  for (int k = 0; k < 9; ++k) {
    // ---- phase 1: bilinear gather for 16 channels of pixel pl ----
    float dy = omb[(size_t)(2 * k) * HW + pxg];
    float dx = omb[(size_t)(2 * k + 1) * HW + pxg];
    float ml = omb[(size_t)(18 + k) * HW + pxg];
    float m = 1.f / (1.f + __expf(-ml));
    float py = (float)(y + (k / 3) - 1) + dy;
    float px = (float)(x + (k % 3) - 1) + dx;
    float y0f = floorf(py), x0f = floorf(px);
    float ly = py - y0f, lx = px - x0f;
    int y0 = (int)y0f, x0 = (int)x0f;
    int y1 = y0 + 1, x1 = x0 + 1;
    float w00 = (1.f - ly) * (1.f - lx) * m;
    float w01 = (1.f - ly) * lx * m;
    float w10 = ly * (1.f - lx) * m;
    float w11 = ly * lx * m;
    bool vy0 = ((unsigned)y0 < (unsigned)H);
    bool vy1 = ((unsigned)y1 < (unsigned)H);
    bool vx0 = ((unsigned)x0 < (unsigned)W);
    bool vx1 = ((unsigned)x1 < (unsigned)W);
    if (!(vy0 && vx0)) w00 = 0.f;
    if (!(vy0 && vx1)) w01 = 0.f;
    if (!(vy1 && vx0)) w10 = 0.f;
    if (!(vy1 && vx1)) w11 = 0.f;
    int cy0 = min(max(y0, 0), H - 1), cy1 = min(max(y1, 0), H - 1);
    int cx0 = min(max(x0, 0), W - 1), cx1 = min(max(x1, 0), W - 1);
    const unsigned short* b00 = fb + (size_t)(cy0 * W + cx0) * 64 + cq * 16;
    const unsigned short* b01 = fb + (size_t)(cy0 * W + cx1) * 64 + cq * 16;
    const unsigned short* b10 = fb + (size_t)(cy1 * W + cx0) * 64 + cq * 16;
    const unsigned short* b11 = fb + (size_t)(cy1 * W + cx1) * 64 + cq * 16;
#pragma unroll
    for (int h = 0; h < 2; ++h) {
      bf16x8 f00 = *(const bf16x8*)(b00 + h * 8);
      bf16x8 f01 = *(const bf16x8*)(b01 + h * 8);
      bf16x8 f10 = *(const bf16x8*)(b10 + h * 8);
      bf16x8 f11 = *(const bf16x8*)(b11 + h * 8);
      bf16x8 vv;
#pragma unroll
      for (int j = 0; j < 8; ++j) {
        float v = w00 * bf2f(f00[j]) + w01 * bf2f(f01[j])
                + w10 * bf2f(f10[j]) + w11 * bf2f(f11[j]);
        vv[j] = (short)f2bf(v);
      }
      *(bf16x8*)(val + pl * 72 + cq * 16 + h * 8) = vv;
    }
    __syncthreads();
    // ---- phase 2: MFMA, wave wv = oc-tile wv ----
    const bf16x8* wp0 = (const bf16x8*)(wf + (((size_t)(k * 2 + 0) * 4 + wv) * 64) * 8);
    const bf16x8* wp1 = (const bf16x8*)(wf + (((size_t)(k * 2 + 1) * 4 + wv) * 64) * 8);
    bf16x8 a0 = wp0[lane];
    bf16x8 a1 = wp1[lane];
#pragma unroll
    for (int q = 0; q < 4; ++q) {
      const int vb = (q * 16 + (lane & 15)) * 72 + (lane >> 4) * 8;
      bf16x8 b0 = *(const bf16x8*)(val + vb);
      bf16x8 b1 = *(const bf16x8*)(val + vb + 32);
      acc[q] = __builtin_amdgcn_mfma_f32_16x16x32_bf16(a0, b0, acc[q], 0, 0, 0);
      acc[q] = __builtin_amdgcn_mfma_f32_16x16x32_bf16(a1, b1, acc[q], 0, 0, 0);
    }
    __syncthreads();
  }

  // C/D: col=lane&15 (px), row=(lane>>4)*4+reg (oc within tile wv)
  float* ob = out + (size_t)b * outBatch + outChOff;
#pragma unroll
  for (int q = 0; q < 4; ++q) {
    int pxw = px0 + q * 16 + (lane & 15);
#pragma unroll
    for (int rg = 0; rg < 4; ++rg) {
      int oc = wv * 16 + (lane >> 4) * 4 + rg;
      ob[(size_t)oc * HW + pxw] = acc[q][rg];
    }
  }
}

// ---------------- 1x1 conv over concat(inA[CINA], inB[CINB]) ----------------
template <int CINA, int CINB, int COUT>
__global__ __launch_bounds__(256) void k_conv1x1(
    const float* __restrict__ inA, const float* __restrict__ inB,
    const float* __restrict__ wT, const float* __restrict__ bias,
    float* __restrict__ out, int HW, long long obatch, long long ochoff) {
  const int b = blockIdx.y;
  const int p = blockIdx.x * 256 + threadIdx.x;
  if (p >= HW) return;
  float acc[COUT];
#pragma unroll
  for (int i = 0; i < COUT; ++i) acc[i] = bias[i];
  const float* pa = inA + (size_t)b * CINA * HW + p;
  for (int c = 0; c < CINA; ++c) {
    float v = pa[(size_t)c * HW];
    const float* w = wT + (size_t)c * COUT;
#pragma unroll
    for (int oc = 0; oc < COUT; ++oc) acc[oc] = fmaf(w[oc], v, acc[oc]);
  }
  const float* pb = inB + (size_t)b * CINB * HW + p;
  for (int c = 0; c < CINB; ++c) {
    float v = pb[(size_t)c * HW];
    const float* w = wT + (size_t)(CINA + c) * COUT;
#pragma unroll
    for (int oc = 0; oc < COUT; ++oc) acc[oc] = fmaf(w[oc], v, acc[oc]);
  }
  float* op = out + (size_t)b * obatch + ochoff + p;
#pragma unroll
  for (int oc = 0; oc < COUT; ++oc) op[(size_t)oc * HW] = acc[oc];
}

// =====================================================================
extern "C" void kernel_launch(void* const* d_in, const int* in_sizes, int n_in,
                              void* d_out, int out_size, void* d_ws, size_t ws_size,
                              hipStream_t stream) {
  const float* feat_c = (const float*)d_in[0];
  const float* feat_n = (const float*)d_in[1];
  const float* w_om1 = (const float*)d_in[2];  const float* b_om1 = (const float*)d_in[3];
  const float* w_om2 = (const float*)d_in[4];  const float* b_om2 = (const float*)d_in[5];
  const float* w_om3 = (const float*)d_in[6];  const float* b_om3 = (const float*)d_in[7];
  const float* w_omc = (const float*)d_in[8];  const float* b_omc = (const float*)d_in[9];
  const float* w_f23 = (const float*)d_in[10]; const float* b_f23 = (const float*)d_in[11];
  const float* w_f12 = (const float*)d_in[12]; const float* b_f12 = (const float*)d_in[13];
  const float* w_a23 = (const float*)d_in[14]; const float* b_a23 = (const float*)d_in[15];
  const float* w_a12 = (const float*)d_in[16]; const float* b_a12 = (const float*)d_in[17];
  const float* w_d1 = (const float*)d_in[18];  const float* b_d1 = (const float*)d_in[19];
  const float* w_d2 = (const float*)d_in[20];  const float* b_d2 = (const float*)d_in[21];
  const float* w_d3 = (const float*)d_in[22];  const float* b_d3 = (const float*)d_in[23];
  const float* w_dc = (const float*)d_in[24];  const float* b_dc = (const float*)d_in[25];

  float* out = (float*)d_out;
  float* ws = (float*)d_ws;

  const int H1 = 128, W1 = 128, HW1s = 16384;
  const int H2 = 64,  W2 = 64,  HW2s = 4096;
  const int H3 = 32,  W3 = 32,  HW3s = 1024;
  const int B = BB;

  // ---- workspace arena (fp32 elements), lifetime-checked aliases ----
  size_t off = 0;
  auto alloc = [&](size_t n) { float* p = ws + off; off += n; return p; };
  float* fc2     = alloc((size_t)B * CC * HW2s);   // aliased later: a2_raw
  float* fn2     = alloc((size_t)B * CC * HW2s);
  float* fc3     = alloc((size_t)B * CC * HW3s);   // aliased later: a3
  float* fn3     = alloc((size_t)B * CC * HW3s);
  float* om3     = alloc((size_t)B * 27 * HW3s);
  float* om2_raw = alloc((size_t)B * 27 * HW2s);
  float* om3_up  = alloc((size_t)B * 27 * HW2s);
  float* om2     = alloc((size_t)B * 27 * HW2s);
  float* om1_raw = alloc((size_t)B * 27 * HW1s);
  float* om2_up  = alloc((size_t)B * 27 * HW1s);   // aliased later: a3_up
  float* a2      = alloc((size_t)B * CC * HW2s);
  float* a1_raw  = alloc((size_t)B * CC * HW1s);
  float* a2_up   = alloc((size_t)B * CC * HW1s);
  float* a1      = alloc((size_t)B * CC * HW1s);
  float* wt_f23  = alloc(27 * 54);
  float* wt_f12  = alloc(27 * 54);
  float* wt_a23  = alloc(64 * 128);
  float* wt_a12  = alloc(64 * 128);
  // conv5 MFMA A-frags (102,400 ushort each)
  unsigned short* wmfa_om1 = (unsigned short*)alloc(51200);
  unsigned short* wmfa_om2 = (unsigned short*)alloc(51200);
  unsigned short* wmfa_om3 = (unsigned short*)alloc(51200);
  unsigned short* wmfa_omc = (unsigned short*)alloc(51200);
  // DCN MFMA A-frags (36,864 ushort each)
  unsigned short* wfd1 = (unsigned short*)alloc(18432);
  unsigned short* wfd2 = (unsigned short*)alloc(18432);
  unsigned short* wfd3 = (unsigned short*)alloc(18432);
  unsigned short* wfdc = (unsigned short*)alloc(18432);
  // channels-last bf16 DCN inputs
  unsigned short* fnT1 = (unsigned short*)alloc((size_t)B * HW1s * 32);  // B*HW*64 us
  unsigned short* fnT2 = (unsigned short*)alloc((size_t)B * HW2s * 32);
  unsigned short* fnT3 = (unsigned short*)alloc((size_t)B * HW3s * 32);
  unsigned short* a1T  = (unsigned short*)alloc((size_t)B * HW1s * 32);
  if (ws_size < off * sizeof(float)) return;  // workspace too small: bail out

  float* a2_raw = fc2;     // fc2 dead after om2_raw conv
  float* a3     = fc3;     // fc3 dead after om3 conv
  float* a3_up  = om2_up;  // om2_up dead after om1

  float* out1 = out + (size_t)B * CC * HW1s;  // second output: [B][54][128][128]

  dim3 blk(256);
  int g;

  // ---- weight preps (read-only inputs; run first) ----
  k_wtrans<<<(27 * 54 + 255) / 256, blk, 0, stream>>>(w_f23, wt_f23, 27, 54, 1);
  k_wtrans<<<(27 * 54 + 255) / 256, blk, 0, stream>>>(w_f12, wt_f12, 27, 54, 1);
  k_wtrans<<<(64 * 128 + 255) / 256, blk, 0, stream>>>(w_a23, wt_a23, 64, 128, 1);
  k_wtrans<<<(64 * 128 + 255) / 256, blk, 0, stream>>>(w_a12, wt_a12, 64, 128, 1);
  g = (100 * 1024 + 255) / 256;
  k_wmfa<<<g, blk, 0, stream>>>(w_om1, wmfa_om1);
  k_wmfa<<<g, blk, 0, stream>>>(w_om2, wmfa_om2);
  k_wmfa<<<g, blk, 0, stream>>>(w_om3, wmfa_om3);
  k_wmfa<<<g, blk, 0, stream>>>(w_omc, wmfa_omc);
  g = (36864 + 255) / 256;
  k_wmfd<<<g, blk, 0, stream>>>(w_d1, wfd1);
  k_wmfd<<<g, blk, 0, stream>>>(w_d2, wfd2);
  k_wmfd<<<g, blk, 0, stream>>>(w_d3, wfd3);
  k_wmfd<<<g, blk, 0, stream>>>(w_dc, wfdc);

  // ---- pyramid downsample ----
  g = ((int)((size_t)B * CC * HW2s) + 255) / 256;
  k_down<<<g, blk, 0, stream>>>(feat_c, fc2, B * CC, H1, W1);
  k_down<<<g, blk, 0, stream>>>(feat_n, fn2, B * CC, H1, W1);
  g = ((int)((size_t)B * CC * HW3s) + 255) / 256;
  k_down<<<g, blk, 0, stream>>>(fc2, fc3, B * CC, H2, W2);
  k_down<<<g, blk, 0, stream>>>(fn2, fn3, B * CC, H2, W2);

  // ---- channels-last copies for DCN inputs ----
  k_cl<<<(B * HW1s * 8 + 255) / 256, blk, 0, stream>>>(feat_n, fnT1, HW1s, B * HW1s * 8);
  k_cl<<<(B * HW2s * 8 + 255) / 256, blk, 0, stream>>>(fn2, fnT2, HW2s, B * HW2s * 8);
  k_cl<<<(B * HW3s * 8 + 255) / 256, blk, 0, stream>>>(fn3, fnT3, HW3s, B * HW3s * 8);

  // ---- offset/mask branch ----
  k_conv5m<<<B * (W3 / 16) * (H3 / 8), blk, 0, stream>>>(
      fc3, fn3, wmfa_om3, b_om3, om3, H3, W3, 27LL * HW3s, 0LL);
  k_conv5m<<<B * (W2 / 16) * (H2 / 8), blk, 0, stream>>>(
      fc2, fn2, wmfa_om2, b_om2, om2_raw, H2, W2, 27LL * HW2s, 0LL);
  g = ((int)((size_t)B * 27 * HW2s) + 255) / 256;
  k_up<<<g, blk, 0, stream>>>(om3, om3_up, B * 27, H3, W3);
  {
    dim3 gg(HW2s / 256, B);
    k_conv1x1<27, 27, 27><<<gg, blk, 0, stream>>>(
        om2_raw, om3_up, wt_f23, b_f23, om2, HW2s, 27LL * HW2s, 0LL);
  }
  k_conv5m<<<B * (W1 / 16) * (H1 / 8), blk, 0, stream>>>(
      feat_c, feat_n, wmfa_om1, b_om1, om1_raw, H1, W1, 27LL * HW1s, 0LL);
  g = ((int)((size_t)B * 27 * HW1s) + 255) / 256;
  k_up<<<g, blk, 0, stream>>>(om2, om2_up, B * 27, H2, W2);
  {
    dim3 gg(HW1s / 256, B);  // om1 -> d_out second output, channels 0..26
    k_conv1x1<27, 27, 27><<<gg, blk, 0, stream>>>(
        om1_raw, om2_up, wt_f12, b_f12, out1, HW1s, 54LL * HW1s, 0LL);
  }

  // ---- aligned-feature branch (MFMA DCN) ----
  {
    dim3 gg(HW3s / 64, B);
    k_dcnm<<<gg, blk, 0, stream>>>(
        fnT3, om3, wfd3, b_d3, a3, H3, W3, 27LL * HW3s, 64LL * HW3s, 0LL);
  }
  {
    dim3 gg(HW2s / 64, B);
    k_dcnm<<<gg, blk, 0, stream>>>(
        fnT2, om2, wfd2, b_d2, a2_raw, H2, W2, 27LL * HW2s, 64LL * HW2s, 0LL);
  }
  g = ((int)((size_t)B * CC * HW2s) + 255) / 256;
  k_up<<<g, blk, 0, stream>>>(a3, a3_up, B * CC, H3, W3);
  {
    dim3 gg(HW2s / 256, B);
    k_conv1x1<64, 64, 64><<<gg, blk, 0, stream>>>(
        a2_raw, a3_up, wt_a23, b_a23, a2, HW2s, 64LL * HW2s, 0LL);
  }
  {
    dim3 gg(HW1s / 64, B);  // om1 read back from d_out (channels 0..26 of [54])
    k_dcnm<<<gg, blk, 0, stream>>>(
        fnT1, out1, wfd1, b_d1, a1_raw, H1, W1, 54LL * HW1s, 64LL * HW1s, 0LL);
  }
  g = ((int)((size_t)B * CC * HW1s) + 255) / 256;
  k_up<<<g, blk, 0, stream>>>(a2, a2_up, B * CC, H2, W2);
  {
    dim3 gg(HW1s / 256, B);
    k_conv1x1<64, 64, 64><<<gg, blk, 0, stream>>>(
        a1_raw, a2_up, wt_a12, b_a12, a1, HW1s, 64LL * HW1s, 0LL);
  }

  // ---- final: omc (-> d_out channels 27..53 of output 1), then ac ----
  k_conv5m<<<B * (W1 / 16) * (H1 / 8), blk, 0, stream>>>(
      feat_c, a1, wmfa_omc, b_omc, out1, H1, W1, 54LL * HW1s, 27LL * HW1s);
  k_cl<<<(B * HW1s * 8 + 255) / 256, blk, 0, stream>>>(a1, a1T, HW1s, B * HW1s * 8);
  {
    dim3 gg(HW1s / 64, B);
    k_dcnm<<<gg, blk, 0, stream>>>(
        a1T, out1 + 27LL * HW1s, wfdc, b_dc, out, H1, W1,
        54LL * HW1s, 64LL * HW1s, 0LL);
  }
}

// Round 12
// 862.877 us; speedup vs baseline: 7.8312x; 1.2820x over previous
//
#include <hip/hip_runtime.h>
#include <cstdint>
#include <cstddef>

// =====================================================================
// PyrDCNAlign — r11: identical to r10 (r11 bench was an infra timeout).
//   r10 change under test: conv5m staging from channels-last bf16
//   [B][HW][64] buffers (shared with DCN) + XCD-bijective swizzle.
// =====================================================================

#define BB 8
#define CC 64

typedef __attribute__((ext_vector_type(8))) short bf16x8;
typedef __attribute__((ext_vector_type(4))) float f32x4;

__device__ inline unsigned short f2bf(float f) {
  unsigned int u = __float_as_uint(f);
  return (unsigned short)((u + 0x7FFFu + ((u >> 16) & 1u)) >> 16);
}
__device__ inline float bf2f(short s) {
  return __uint_as_float(((unsigned int)(unsigned short)s) << 16);
}

// ---------------- bicubic resize, scale 0.5 (fixed weights) ----------------
__global__ __launch_bounds__(256) void k_down(const float* __restrict__ in,
                                              float* __restrict__ out,
                                              int BC, int Hin, int Win) {
  const int Ho = Hin >> 1, Wo = Win >> 1;
  const float W4[4] = {-0.09375f, 0.59375f, 0.59375f, -0.09375f};
  int total = BC * Ho * Wo;
  for (int idx = blockIdx.x * 256 + threadIdx.x; idx < total; idx += gridDim.x * 256) {
    int x = idx % Wo;
    int y = (idx / Wo) % Ho;
    int bc = idx / (Wo * Ho);
    const float* src = in + (size_t)bc * Hin * Win;
    float s = 0.f;
#pragma unroll
    for (int i = 0; i < 4; ++i) {
      int yy = 2 * y - 1 + i;
      yy = min(max(yy, 0), Hin - 1);
      const float* row = src + (size_t)yy * Win;
      float rs = 0.f;
#pragma unroll
      for (int j = 0; j < 4; ++j) {
        int xx = 2 * x - 1 + j;
        xx = min(max(xx, 0), Win - 1);
        rs = fmaf(W4[j], row[xx], rs);
      }
      s = fmaf(W4[i], rs, s);
    }
    out[idx] = s;
  }
}

// ---------------- bicubic resize, scale 2.0 (fixed weights by parity) -------
__global__ __launch_bounds__(256) void k_up(const float* __restrict__ in,
                                            float* __restrict__ out,
                                            int BC, int Hin, int Win) {
  const int Ho = Hin << 1, Wo = Win << 1;
  const float WE[4] = {-0.03515625f, 0.26171875f, 0.87890625f, -0.10546875f};
  int total = BC * Ho * Wo;
  for (int idx = blockIdx.x * 256 + threadIdx.x; idx < total; idx += gridDim.x * 256) {
    int x = idx % Wo;
    int y = (idx / Wo) % Ho;
    int bc = idx / (Wo * Ho);
    const float* src = in + (size_t)bc * Hin * Win;
    int fy = (y & 1) ? (y >> 1) : (y >> 1) - 1;
    int fx = (x & 1) ? (x >> 1) : (x >> 1) - 1;
    float s = 0.f;
#pragma unroll
    for (int i = 0; i < 4; ++i) {
      float wy = (y & 1) ? WE[3 - i] : WE[i];
      int yy = min(max(fy - 1 + i, 0), Hin - 1);
      const float* row = src + (size_t)yy * Win;
      float rs = 0.f;
#pragma unroll
      for (int j = 0; j < 4; ++j) {
        float wx = (x & 1) ? WE[3 - j] : WE[j];
        int xx = min(max(fx - 1 + j, 0), Win - 1);
        rs = fmaf(wx, row[xx], rs);
      }
      s = fmaf(wy, rs, s);
    }
    out[idx] = s;
  }
}

// ---------------- weight transpose: [O][Ci][K] -> [K][Ci][O] ----------------
__global__ __launch_bounds__(256) void k_wtrans(const float* __restrict__ in,
                                                float* __restrict__ out,
                                                int COUT, int CIN, int K) {
  int total = COUT * CIN * K;
  int i = blockIdx.x * 256 + threadIdx.x;
  if (i >= total) return;
  int k = i % K;
  int c = (i / K) % CIN;
  int oc = i / (K * CIN);
  out[((size_t)k * CIN + c) * COUT + oc] = in[i];
}

// ------- conv5 MFMA weight prep: w[27][128][25] -> per-lane A-frags --------
__global__ __launch_bounds__(256) void k_wmfa(const float* __restrict__ w,
                                              unsigned short* __restrict__ o) {
  int i = blockIdx.x * 256 + threadIdx.x;
  if (i >= 100 * 1024) return;
  int j = i & 7;
  int lane = (i >> 3) & 63;
  int sm = i >> 9;           // step*2 + m
  int m = sm & 1;
  int step = sm >> 1;        // ccg*25 + tap
  int ccg = step / 25, tap = step - ccg * 25;
  int oc = m * 16 + (lane & 15);
  int cc = ccg * 32 + (lane >> 4) * 8 + j;
  float v = (oc < 27) ? w[((size_t)oc * 128 + cc) * 25 + tap] : 0.f;
  o[i] = f2bf(v);
}

// ------- DCN MFMA weight prep: w[64][64][9] -> per-lane A-frags ------------
__global__ __launch_bounds__(256) void k_wmfd(const float* __restrict__ w,
                                              unsigned short* __restrict__ o) {
  int i = blockIdx.x * 256 + threadIdx.x;
  if (i >= 18 * 4 * 512) return;
  int j = i & 7;
  int lane = (i >> 3) & 63;
  int m = (i >> 9) & 3;
  int step = i >> 11;        // k*2 + ks
  int ks = step & 1, k = step >> 1;
  int oc = m * 16 + (lane & 15);
  int c = ks * 32 + (lane >> 4) * 8 + j;
  o[i] = f2bf(w[((size_t)oc * 64 + c) * 9 + k]);
}

// ------- channels-last bf16: in[B][64][HW] f32 -> o[B][HW][64] bf16 --------
__global__ __launch_bounds__(256) void k_cl(const float* __restrict__ in,
                                            unsigned short* __restrict__ o,
                                            int HW, int total) {
  int i = blockIdx.x * 256 + threadIdx.x;   // i = (b*HW + hw)*8 + cg
  if (i >= total) return;
  int cg = i & 7;
  int r = i >> 3;
  int hw = r % HW;
  int b = r / HW;
  const float* src = in + ((size_t)b * 64 + cg * 8) * HW + hw;
  bf16x8 v;
#pragma unroll
  for (int j = 0; j < 8; ++j) v[j] = (short)f2bf(src[(size_t)j * HW]);
  *(bf16x8*)(o + ((size_t)b * HW + hw) * 64 + cg * 8) = v;
}

// ---------------- 5x5 conv via bf16 MFMA, Cin=64+64, pad=2 ------------------
// Inputs channels-last bf16 [B][HW][64] (A=ch0..63, B=ch64..127).
// Block 256thr/4 waves; output tile 32oc(27) x (16w x 8h) px.
// LDS act[pos(20x12)][136ch]; staged once (bf16x8 vector copy).
__global__ __launch_bounds__(256) void k_conv5m(
    const unsigned short* __restrict__ inAT, const unsigned short* __restrict__ inBT,
    const unsigned short* __restrict__ wmfa, const float* __restrict__ bias,
    float* __restrict__ out, int H, int W,
    long long obatch, long long ochoff) {
  __shared__ unsigned short act[240 * 136];  // 65,280 B
  const int tilesX = W >> 4;
  const int tilesY = H >> 3;
  const int tpb = tilesX * tilesY;
  // XCD-bijective swizzle (gridDim.x divisible by 8: 1024/256/64)
  const int cpx = (int)gridDim.x >> 3;
  const int bid = ((int)blockIdx.x & 7) * cpx + ((int)blockIdx.x >> 3);
  const int b = bid / tpb;
  const int t = bid - b * tpb;
  const int ty0 = (t / tilesX) << 3;
  const int tx0 = (t % tilesX) << 4;
  const int HW = H * W;
  const int lane = threadIdx.x & 63;
  const int wv = threadIdx.x >> 6;

  // stage halo 20x12 x 128ch: 240 pos x 16 ch-groups, vector copies
  for (int i = threadIdx.x; i < 3840; i += 256) {
    int pos = i >> 4, cg = i & 15;
    int hy = pos / 20, hx = pos - hy * 20;
    int gy = ty0 + hy - 2, gx = tx0 + hx - 2;
    bf16x8 v = {0, 0, 0, 0, 0, 0, 0, 0};
    if (gy >= 0 && gy < H && gx >= 0 && gx < W) {
      const unsigned short* sa =
          (cg < 8) ? inAT + ((size_t)b * HW + gy * W + gx) * 64 + cg * 8
                   : inBT + ((size_t)b * HW + gy * W + gx) * 64 + (cg - 8) * 8;
      v = *(const bf16x8*)sa;
    }
    *(bf16x8*)(act + pos * 136 + cg * 8) = v;
  }
  __syncthreads();

  const int pxx = lane & 15;
  const int kg = lane >> 4;

  f32x4 acc[2][2];
#pragma unroll
  for (int m = 0; m < 2; ++m)
#pragma unroll
    for (int r = 0; r < 2; ++r)
#pragma unroll
      for (int q = 0; q < 4; ++q) {
        int oc = m * 16 + kg * 4 + q;
        acc[m][r][q] = (oc < 27) ? bias[oc] : 0.f;
      }

  const int rowbase = (2 * wv) * 20 + pxx;
  const int cbase = kg * 8;

  for (int ccg = 0; ccg < 4; ++ccg) {
    const int coff = ccg * 32 + cbase;
#pragma unroll
    for (int tap = 0; tap < 25; ++tap) {
      const int step = ccg * 25 + tap;
      const bf16x8* wp = (const bf16x8*)(wmfa + (size_t)step * 1024);
      bf16x8 a0 = wp[lane];
      bf16x8 a1 = wp[64 + lane];
      const int dy = tap / 5, dx = tap - 5 * (tap / 5);
      const int base0 = (rowbase + dy * 20 + dx) * 136 + coff;
      bf16x8 b0 = *(const bf16x8*)(act + base0);
      bf16x8 b1 = *(const bf16x8*)(act + base0 + 20 * 136);
      acc[0][0] = __builtin_amdgcn_mfma_f32_16x16x32_bf16(a0, b0, acc[0][0], 0, 0, 0);
      acc[0][1] = __builtin_amdgcn_mfma_f32_16x16x32_bf16(a0, b1, acc[0][1], 0, 0, 0);
      acc[1][0] = __builtin_amdgcn_mfma_f32_16x16x32_bf16(a1, b0, acc[1][0], 0, 0, 0);
      acc[1][1] = __builtin_amdgcn_mfma_f32_16x16x32_bf16(a1, b1, acc[1][1], 0, 0, 0);
    }
  }

#pragma unroll
  for (int m = 0; m < 2; ++m)
#pragma unroll
    for (int r = 0; r < 2; ++r) {
      int py = 2 * wv + r;
      float* op = out + (size_t)b * obatch + ochoff + (size_t)(ty0 + py) * W + tx0 + pxx;
#pragma unroll
      for (int q = 0; q < 4; ++q) {
        int oc = m * 16 + kg * 4 + q;
        if (oc < 27) op[(size_t)oc * HW] = acc[m][r][q];
      }
    }
}

// ---------------- modulated DCN 3x3 via bf16 MFMA ---------------------------
__global__ __launch_bounds__(256) void k_dcnm(
    const unsigned short* __restrict__ fnT, const float* __restrict__ om,
    const unsigned short* __restrict__ wf, const float* __restrict__ bias,
    float* __restrict__ out, int H, int W,
    long long omBatch, long long outBatch, long long outChOff) {
  __shared__ unsigned short val[64 * 72];  // 9216 B
  const int b = blockIdx.y;
  const int HW = H * W;
  const int px0 = blockIdx.x * 64;
  const int tid = threadIdx.x;
  const int lane = tid & 63;
  const int wv = tid >> 6;
  const int pl = lane;
  const int cq = wv;
  const int pxg = px0 + pl;
  const int y = pxg / W, x = pxg - y * W;
  const float* omb = om + (size_t)b * omBatch;
  const unsigned short* fb = fnT + (size_t)b * HW * 64;

  f32x4 acc[4];
#pragma unroll
  for (int q = 0; q < 4; ++q)
#pragma unroll
    for (int rg = 0; rg < 4; ++rg)
      acc[q][rg] = bias[wv * 16 + (lane >> 4) * 4 + rg];

  for (int k = 0; k < 9; ++k) {
    float dy = omb[(size_t)(2 * k) * HW + pxg];
    float dx = omb[(size_t)(2 * k + 1) * HW + pxg];
    float ml = omb[(size_t)(18 + k) * HW + pxg];
    float m = 1.f / (1.f + __expf(-ml));
    float py = (float)(y + (k / 3) - 1) + dy;
    float px = (float)(x + (k % 3) - 1) + dx;
    float y0f = floorf(py), x0f = floorf(px);
    float ly = py - y0f, lx = px - x0f;
    int y0 = (int)y0f, x0 = (int)x0f;
    int y1 = y0 + 1, x1 = x0 + 1;
    float w00 = (1.f - ly) * (1.f - lx) * m;
    float w01 = (1.f - ly) * lx * m;
    float w10 = ly * (1.f - lx) * m;
    float w11 = ly * lx * m;
    bool vy0 = ((unsigned)y0 < (unsigned)H);
    bool vy1 = ((unsigned)y1 < (unsigned)H);
    bool vx0 = ((unsigned)x0 < (unsigned)W);
    bool vx1 = ((unsigned)x1 < (unsigned)W);
    if (!(vy0 && vx0)) w00 = 0.f;
    if (!(vy0 && vx1)) w01 = 0.f;
    if (!(vy1 && vx0)) w10 = 0.f;
    if (!(vy1 && vx1)) w11 = 0.f;
    int cy0 = min(max(y0, 0), H - 1), cy1 = min(max(y1, 0), H - 1);
    int cx0 = min(max(x0, 0), W - 1), cx1 = min(max(x1, 0), W - 1);
    const unsigned short* b00 = fb + (size_t)(cy0 * W + cx0) * 64 + cq * 16;
    const unsigned short* b01 = fb + (size_t)(cy0 * W + cx1) * 64 + cq * 16;
    const unsigned short* b10 = fb + (size_t)(cy1 * W + cx0) * 64 + cq * 16;
    const unsigned short* b11 = fb + (size_t)(cy1 * W + cx1) * 64 + cq * 16;
#pragma unroll
    for (int h = 0; h < 2; ++h) {
      bf16x8 f00 = *(const bf16x8*)(b00 + h * 8);
      bf16x8 f01 = *(const bf16x8*)(b01 + h * 8);
      bf16x8 f10 = *(const bf16x8*)(b10 + h * 8);
      bf16x8 f11 = *(const bf16x8*)(b11 + h * 8);
      bf16x8 vv;
#pragma unroll
      for (int j = 0; j < 8; ++j) {
        float v = w00 * bf2f(f00[j]) + w01 * bf2f(f01[j])
                + w10 * bf2f(f10[j]) + w11 * bf2f(f11[j]);
        vv[j] = (short)f2bf(v);
      }
      *(bf16x8*)(val + pl * 72 + cq * 16 + h * 8) = vv;
    }
    __syncthreads();
    const bf16x8* wp0 = (const bf16x8*)(wf + (((size_t)(k * 2 + 0) * 4 + wv) * 64) * 8);
    const bf16x8* wp1 = (const bf16x8*)(wf + (((size_t)(k * 2 + 1) * 4 + wv) * 64) * 8);
    bf16x8 a0 = wp0[lane];
    bf16x8 a1 = wp1[lane];
#pragma unroll
    for (int q = 0; q < 4; ++q) {
      const int vb = (q * 16 + (lane & 15)) * 72 + (lane >> 4) * 8;
      bf16x8 b0 = *(const bf16x8*)(val + vb);
      bf16x8 b1 = *(const bf16x8*)(val + vb + 32);
      acc[q] = __builtin_amdgcn_mfma_f32_16x16x32_bf16(a0, b0, acc[q], 0, 0, 0);
      acc[q] = __builtin_amdgcn_mfma_f32_16x16x32_bf16(a1, b1, acc[q], 0, 0, 0);
    }
    __syncthreads();
  }

  float* ob = out + (size_t)b * outBatch + outChOff;
#pragma unroll
  for (int q = 0; q < 4; ++q) {
    int pxw = px0 + q * 16 + (lane & 15);
#pragma unroll
    for (int rg = 0; rg < 4; ++rg) {
      int oc = wv * 16 + (lane >> 4) * 4 + rg;
      ob[(size_t)oc * HW + pxw] = acc[q][rg];
    }
  }
}

// ---------------- 1x1 conv over concat(inA[CINA], inB[CINB]) ----------------
template <int CINA, int CINB, int COUT>
__global__ __launch_bounds__(256) void k_conv1x1(
    const float* __restrict__ inA, const float* __restrict__ inB,
    const float* __restrict__ wT, const float* __restrict__ bias,
    float* __restrict__ out, int HW, long long obatch, long long ochoff) {
  const int b = blockIdx.y;
  const int p = blockIdx.x * 256 + threadIdx.x;
  if (p >= HW) return;
  float acc[COUT];
#pragma unroll
  for (int i = 0; i < COUT; ++i) acc[i] = bias[i];
  const float* pa = inA + (size_t)b * CINA * HW + p;
  for (int c = 0; c < CINA; ++c) {
    float v = pa[(size_t)c * HW];
    const float* w = wT + (size_t)c * COUT;
#pragma unroll
    for (int oc = 0; oc < COUT; ++oc) acc[oc] = fmaf(w[oc], v, acc[oc]);
  }
  const float* pb = inB + (size_t)b * CINB * HW + p;
  for (int c = 0; c < CINB; ++c) {
    float v = pb[(size_t)c * HW];
    const float* w = wT + (size_t)(CINA + c) * COUT;
#pragma unroll
    for (int oc = 0; oc < COUT; ++oc) acc[oc] = fmaf(w[oc], v, acc[oc]);
  }
  float* op = out + (size_t)b * obatch + ochoff + p;
#pragma unroll
  for (int oc = 0; oc < COUT; ++oc) op[(size_t)oc * HW] = acc[oc];
}

// =====================================================================
extern "C" void kernel_launch(void* const* d_in, const int* in_sizes, int n_in,
                              void* d_out, int out_size, void* d_ws, size_t ws_size,
                              hipStream_t stream) {
  const float* feat_c = (const float*)d_in[0];
  const float* feat_n = (const float*)d_in[1];
  const float* w_om1 = (const float*)d_in[2];  const float* b_om1 = (const float*)d_in[3];
  const float* w_om2 = (const float*)d_in[4];  const float* b_om2 = (const float*)d_in[5];
  const float* w_om3 = (const float*)d_in[6];  const float* b_om3 = (const float*)d_in[7];
  const float* w_omc = (const float*)d_in[8];  const float* b_omc = (const float*)d_in[9];
  const float* w_f23 = (const float*)d_in[10]; const float* b_f23 = (const float*)d_in[11];
  const float* w_f12 = (const float*)d_in[12]; const float* b_f12 = (const float*)d_in[13];
  const float* w_a23 = (const float*)d_in[14]; const float* b_a23 = (const float*)d_in[15];
  const float* w_a12 = (const float*)d_in[16]; const float* b_a12 = (const float*)d_in[17];
  const float* w_d1 = (const float*)d_in[18];  const float* b_d1 = (const float*)d_in[19];
  const float* w_d2 = (const float*)d_in[20];  const float* b_d2 = (const float*)d_in[21];
  const float* w_d3 = (const float*)d_in[22];  const float* b_d3 = (const float*)d_in[23];
  const float* w_dc = (const float*)d_in[24];  const float* b_dc = (const float*)d_in[25];

  float* out = (float*)d_out;
  float* ws = (float*)d_ws;

  const int H1 = 128, W1 = 128, HW1s = 16384;
  const int H2 = 64,  W2 = 64,  HW2s = 4096;
  const int H3 = 32,  W3 = 32,  HW3s = 1024;
  const int B = BB;

  // ---- workspace arena (fp32 elements), lifetime-checked aliases ----
  size_t off = 0;
  auto alloc = [&](size_t n) { float* p = ws + off; off += n; return p; };
  float* fc2     = alloc((size_t)B * CC * HW2s);   // aliased later: a2_raw
  float* fn2     = alloc((size_t)B * CC * HW2s);
  float* fc3     = alloc((size_t)B * CC * HW3s);   // aliased later: a3
  float* fn3     = alloc((size_t)B * CC * HW3s);
  float* om3     = alloc((size_t)B * 27 * HW3s);
  float* om2_raw = alloc((size_t)B * 27 * HW2s);
  float* om3_up  = alloc((size_t)B * 27 * HW2s);
  float* om2     = alloc((size_t)B * 27 * HW2s);
  float* om1_raw = alloc((size_t)B * 27 * HW1s);
  float* om2_up  = alloc((size_t)B * 27 * HW1s);   // aliased later: a3_up
  float* a2      = alloc((size_t)B * CC * HW2s);
  float* a1_raw  = alloc((size_t)B * CC * HW1s);
  float* a2_up   = alloc((size_t)B * CC * HW1s);
  float* a1      = alloc((size_t)B * CC * HW1s);
  float* wt_f23  = alloc(27 * 54);
  float* wt_f12  = alloc(27 * 54);
  float* wt_a23  = alloc(64 * 128);
  float* wt_a12  = alloc(64 * 128);
  // conv5 MFMA A-frags
  unsigned short* wmfa_om1 = (unsigned short*)alloc(51200);
  unsigned short* wmfa_om2 = (unsigned short*)alloc(51200);
  unsigned short* wmfa_om3 = (unsigned short*)alloc(51200);
  unsigned short* wmfa_omc = (unsigned short*)alloc(51200);
  // DCN MFMA A-frags
  unsigned short* wfd1 = (unsigned short*)alloc(18432);
  unsigned short* wfd2 = (unsigned short*)alloc(18432);
  unsigned short* wfd3 = (unsigned short*)alloc(18432);
  unsigned short* wfdc = (unsigned short*)alloc(18432);
  // channels-last bf16 buffers (shared by conv5m staging and DCN gather)
  unsigned short* fcT1 = (unsigned short*)alloc((size_t)B * HW1s * 32);
  unsigned short* fnT1 = (unsigned short*)alloc((size_t)B * HW1s * 32);
  unsigned short* fc2T = (unsigned short*)alloc((size_t)B * HW2s * 32);
  unsigned short* fn2T = (unsigned short*)alloc((size_t)B * HW2s * 32);
  unsigned short* fc3T = (unsigned short*)alloc((size_t)B * HW3s * 32);
  unsigned short* fn3T = (unsigned short*)alloc((size_t)B * HW3s * 32);
  unsigned short* a1T  = (unsigned short*)alloc((size_t)B * HW1s * 32);
  if (ws_size < off * sizeof(float)) return;  // workspace too small: bail out

  float* a2_raw = fc2;     // fc2 dead after om2_raw conv
  float* a3     = fc3;     // fc3 dead after om3 conv
  float* a3_up  = om2_up;  // om2_up dead after om1

  float* out1 = out + (size_t)B * CC * HW1s;  // second output: [B][54][128][128]

  dim3 blk(256);
  int g;

  // ---- weight preps (read-only inputs; run first) ----
  k_wtrans<<<(27 * 54 + 255) / 256, blk, 0, stream>>>(w_f23, wt_f23, 27, 54, 1);
  k_wtrans<<<(27 * 54 + 255) / 256, blk, 0, stream>>>(w_f12, wt_f12, 27, 54, 1);
  k_wtrans<<<(64 * 128 + 255) / 256, blk, 0, stream>>>(w_a23, wt_a23, 64, 128, 1);
  k_wtrans<<<(64 * 128 + 255) / 256, blk, 0, stream>>>(w_a12, wt_a12, 64, 128, 1);
  g = (100 * 1024 + 255) / 256;
  k_wmfa<<<g, blk, 0, stream>>>(w_om1, wmfa_om1);
  k_wmfa<<<g, blk, 0, stream>>>(w_om2, wmfa_om2);
  k_wmfa<<<g, blk, 0, stream>>>(w_om3, wmfa_om3);
  k_wmfa<<<g, blk, 0, stream>>>(w_omc, wmfa_omc);
  g = (36864 + 255) / 256;
  k_wmfd<<<g, blk, 0, stream>>>(w_d1, wfd1);
  k_wmfd<<<g, blk, 0, stream>>>(w_d2, wfd2);
  k_wmfd<<<g, blk, 0, stream>>>(w_d3, wfd3);
  k_wmfd<<<g, blk, 0, stream>>>(w_dc, wfdc);

  // ---- pyramid downsample ----
  g = ((int)((size_t)B * CC * HW2s) + 255) / 256;
  k_down<<<g, blk, 0, stream>>>(feat_c, fc2, B * CC, H1, W1);
  k_down<<<g, blk, 0, stream>>>(feat_n, fn2, B * CC, H1, W1);
  g = ((int)((size_t)B * CC * HW3s) + 255) / 256;
  k_down<<<g, blk, 0, stream>>>(fc2, fc3, B * CC, H2, W2);
  k_down<<<g, blk, 0, stream>>>(fn2, fn3, B * CC, H2, W2);

  // ---- channels-last bf16 conversions ----
  k_cl<<<(B * HW1s * 8 + 255) / 256, blk, 0, stream>>>(feat_c, fcT1, HW1s, B * HW1s * 8);
  k_cl<<<(B * HW1s * 8 + 255) / 256, blk, 0, stream>>>(feat_n, fnT1, HW1s, B * HW1s * 8);
  k_cl<<<(B * HW2s * 8 + 255) / 256, blk, 0, stream>>>(fc2, fc2T, HW2s, B * HW2s * 8);
  k_cl<<<(B * HW2s * 8 + 255) / 256, blk, 0, stream>>>(fn2, fn2T, HW2s, B * HW2s * 8);
  k_cl<<<(B * HW3s * 8 + 255) / 256, blk, 0, stream>>>(fc3, fc3T, HW3s, B * HW3s * 8);
  k_cl<<<(B * HW3s * 8 + 255) / 256, blk, 0, stream>>>(fn3, fn3T, HW3s, B * HW3s * 8);

  // ---- offset/mask branch ----
  k_conv5m<<<B * (W3 / 16) * (H3 / 8), blk, 0, stream>>>(
      fc3T, fn3T, wmfa_om3, b_om3, om3, H3, W3, 27LL * HW3s, 0LL);
  k_conv5m<<<B * (W2 / 16) * (H2 / 8), blk, 0, stream>>>(
      fc2T, fn2T, wmfa_om2, b_om2, om2_raw, H2, W2, 27LL * HW2s, 0LL);
  g = ((int)((size_t)B * 27 * HW2s) + 255) / 256;
  k_up<<<g, blk, 0, stream>>>(om3, om3_up, B * 27, H3, W3);
  {
    dim3 gg(HW2s / 256, B);
    k_conv1x1<27, 27, 27><<<gg, blk, 0, stream>>>(
        om2_raw, om3_up, wt_f23, b_f23, om2, HW2s, 27LL * HW2s, 0LL);
  }
  k_conv5m<<<B * (W1 / 16) * (H1 / 8), blk, 0, stream>>>(
      fcT1, fnT1, wmfa_om1, b_om1, om1_raw, H1, W1, 27LL * HW1s, 0LL);
  g = ((int)((size_t)B * 27 * HW1s) + 255) / 256;
  k_up<<<g, blk, 0, stream>>>(om2, om2_up, B * 27, H2, W2);
  {
    dim3 gg(HW1s / 256, B);  // om1 -> d_out second output, channels 0..26
    k_conv1x1<27, 27, 27><<<gg, blk, 0, stream>>>(
        om1_raw, om2_up, wt_f12, b_f12, out1, HW1s, 54LL * HW1s, 0LL);
  }

  // ---- aligned-feature branch (MFMA DCN) ----
  {
    dim3 gg(HW3s / 64, B);
    k_dcnm<<<gg, blk, 0, stream>>>(
        fn3T, om3, wfd3, b_d3, a3, H3, W3, 27LL * HW3s, 64LL * HW3s, 0LL);
  }
  {
    dim3 gg(HW2s / 64, B);
    k_dcnm<<<gg, blk, 0, stream>>>(
        fn2T, om2, wfd2, b_d2, a2_raw, H2, W2, 27LL * HW2s, 64LL * HW2s, 0LL);
  }
  g = ((int)((size_t)B * CC * HW2s) + 255) / 256;
  k_up<<<g, blk, 0, stream>>>(a3, a3_up, B * CC, H3, W3);
  {
    dim3 gg(HW2s / 256, B);
    k_conv1x1<64, 64, 64><<<gg, blk, 0, stream>>>(
        a2_raw, a3_up, wt_a23, b_a23, a2, HW2s, 64LL * HW2s, 0LL);
  }
  {
    dim3 gg(HW1s / 64, B);  // om1 read back from d_out (channels 0..26 of [54])
    k_dcnm<<<gg, blk, 0, stream>>>(
        fnT1, out1, wfd1, b_d1, a1_raw, H1, W1, 54LL * HW1s, 64LL * HW1s, 0LL);
  }
  g = ((int)((size_t)B * CC * HW1s) + 255) / 256;
  k_up<<<g, blk, 0, stream>>>(a2, a2_up, B * CC, H2, W2);
  {
    dim3 gg(HW1s / 256, B);
    k_conv1x1<64, 64, 64><<<gg, blk, 0, stream>>>(
        a1_raw, a2_up, wt_a12, b_a12, a1, HW1s, 64LL * HW1s, 0LL);
  }

  // ---- final: a1 -> CL, omc conv5m(fcT1, a1T), then ac dcnm ----
  k_cl<<<(B * HW1s * 8 + 255) / 256, blk, 0, stream>>>(a1, a1T, HW1s, B * HW1s * 8);
  k_conv5m<<<B * (W1 / 16) * (H1 / 8), blk, 0, stream>>>(
      fcT1, a1T, wmfa_omc, b_omc, out1, H1, W1, 54LL * HW1s, 27LL * HW1s);
  {
    dim3 gg(HW1s / 64, B);
    k_dcnm<<<gg, blk, 0, stream>>>(
        a1T, out1 + 27LL * HW1s, wfdc, b_dc, out, H1, W1,
        54LL * HW1s, 64LL * HW1s, 0LL);
  }
}